// Round 9
// baseline (7508.167 us; speedup 1.0000x reference)
//
#include <hip/hip_runtime.h>
#include <hip/hip_cooperative_groups.h>

namespace cg = cooperative_groups;

#define H 128
#define IN_DIM 256
#define OUT_DIM 40
#define EPS 1e-5f

typedef unsigned short ushortT;
typedef __attribute__((ext_vector_type(8))) short bf16x8;
typedef __attribute__((ext_vector_type(4))) float f32x4;

static __device__ __forceinline__ ushortT f2bf(float f) {
    union { float f; unsigned u; } v; v.f = f;
    unsigned r = v.u + 0x7FFF + ((v.u >> 16) & 1);   // RNE
    return (ushortT)(r >> 16);
}
static __device__ __forceinline__ unsigned pk2(float a, float b) {
    return (unsigned)f2bf(a) | ((unsigned)f2bf(b) << 16);
}
static __device__ __forceinline__ float bflo(unsigned v) {
    union { unsigned u; float f; } t; t.u = v << 16; return t.f;
}
static __device__ __forceinline__ float bfhi(unsigned v) {
    union { unsigned u; float f; } t; t.u = v & 0xFFFF0000u; return t.f;
}
static __device__ __forceinline__ float i2f(int v) {
    union { int i; float f; } t; t.i = v; return t.f;
}
static __device__ __forceinline__ int f2i(float v) {
    union { float f; int i; } t; t.f = v; return t.i;
}

struct MegaParams {
    const float* x; const int* ei;
    const float* W0; const float* g0; const float* be0;
    const float* pW; const float* pb;
    const float* W1; const float* g1; const float* be1;
    const float* hW; const float* hb;
    float* out;
    ushortT* hb16; ushortT* aggb; ushortT* projb; ushortT* x1b;
    float* dis; int* cnt; int* rowptr; int* cursor; int2* recs;
    float* stats;                       // [512]: conv0 sums then conv1 sums
    ushortT* Wt0; ushortT* WtP; ushortT* Wt1; ushortT* WtH;
    int* bsum; int* boff;
    int N; int E;
};

// ---- GEMM0 helpers (identical math to R8 mgemm0d) ----
static __device__ __forceinline__ void g0l(const float* __restrict__ X, int brow, int kc,
                                           int tid, int N, float4 pf[4]) {
#pragma unroll
    for (int i = 0; i < 4; ++i) {
        int idx = i * 512 + tid;
        int row = idx >> 5, c4 = idx & 31;
        int gr = brow + row;
        pf[i] = make_float4(0.f, 0.f, 0.f, 0.f);
        if (gr < N) pf[i] = *(const float4*)&X[(size_t)gr * IN_DIM + kc * 128 + c4 * 4];
    }
}
static __device__ __forceinline__ void g0w(ushortT* __restrict__ Sbuf, int tid, const float4 pf[4]) {
#pragma unroll
    for (int i = 0; i < 4; ++i) {
        int idx = i * 512 + tid;
        int row = idx >> 5, c4 = idx & 31;
        uint2 p;
        p.x = pk2(pf[i].x, pf[i].y);
        p.y = pk2(pf[i].z, pf[i].w);
        *(uint2*)&Sbuf[row * 136 + c4 * 4] = p;
    }
}

// ---- aggregation phase (R8 aggregate_rec, wave-stride) ----
static __device__ void agg_phase(const ushortT* __restrict__ h, const int* __restrict__ rowptr,
                                 const int2* __restrict__ recs, ushortT* __restrict__ aggb,
                                 int N, int gw, int nW, int lane) {
    int half = lane >> 5, cl = lane & 31;
    const uint2* h2 = (const uint2*)h;
    for (int n = gw; n < N; n += nW) {
        int beg = rowptr[n], end = rowptr[n + 1];
        float a0 = 0.f, a1 = 0.f, a2 = 0.f, a3 = 0.f;
        float b0 = 0.f, b1 = 0.f, b2 = 0.f, b3 = 0.f;
        int idx = beg + half;
        for (; idx + 2 < end; idx += 4) {
            int2 r0 = recs[idx];
            int2 r1 = recs[idx + 2];
            uint2 v0 = h2[(size_t)r0.x * 32 + cl];
            uint2 v1 = h2[(size_t)r1.x * 32 + cl];
            float n0 = i2f(r0.y), n1 = i2f(r1.y);
            a0 = fmaf(n0, bflo(v0.x), a0); a1 = fmaf(n0, bfhi(v0.x), a1);
            a2 = fmaf(n0, bflo(v0.y), a2); a3 = fmaf(n0, bfhi(v0.y), a3);
            b0 = fmaf(n1, bflo(v1.x), b0); b1 = fmaf(n1, bfhi(v1.x), b1);
            b2 = fmaf(n1, bflo(v1.y), b2); b3 = fmaf(n1, bfhi(v1.y), b3);
        }
        if (idx < end) {
            int2 r0 = recs[idx];
            uint2 v0 = h2[(size_t)r0.x * 32 + cl];
            float n0 = i2f(r0.y);
            a0 = fmaf(n0, bflo(v0.x), a0); a1 = fmaf(n0, bfhi(v0.x), a1);
            a2 = fmaf(n0, bflo(v0.y), a2); a3 = fmaf(n0, bfhi(v0.y), a3);
        }
        a0 += b0; a1 += b1; a2 += b2; a3 += b3;
        a0 += __shfl_xor(a0, 32);
        a1 += __shfl_xor(a1, 32);
        a2 += __shfl_xor(a2, 32);
        a3 += __shfl_xor(a3, 32);
        if (half == 0) {
            uint2 o;
            o.x = pk2(a0, a1);
            o.y = pk2(a2, a3);
            ((uint2*)aggb)[(size_t)n * 32 + cl] = o;
        }
    }
}

// ---- BN stats phase (R8 stats_bf, 512-thread blocks, LDS overlay) ----
static __device__ void stats_phase(const unsigned* __restrict__ v, int totalU, float* __restrict__ sums,
                                   int gt, int GT, int tid, float* lds) {
    float sx = 0.f, sy = 0.f, qx = 0.f, qy = 0.f;
    for (int i = gt; i < totalU; i += GT) {
        unsigned u = v[i];
        float a = bflo(u), b = bfhi(u);
        sx += a; sy += b;
        qx = fmaf(a, a, qx); qy = fmaf(b, b, qy);
    }
    float* L0 = lds; float* L1 = lds + 512; float* L2 = lds + 1024; float* L3 = lds + 1536;
    L0[tid] = sx; L1[tid] = sy; L2[tid] = qx; L3[tid] = qy;
    __syncthreads();
    if (tid < 64) {
        float s0 = 0.f, s1 = 0.f, s2 = 0.f, s3 = 0.f;
#pragma unroll
        for (int k = 0; k < 8; ++k) {
            s0 += L0[tid + k * 64]; s1 += L1[tid + k * 64];
            s2 += L2[tid + k * 64]; s3 += L3[tid + k * 64];
        }
        atomicAdd(&sums[2 * tid], s0);
        atomicAdd(&sums[2 * tid + 1], s1);
        atomicAdd(&sums[128 + 2 * tid], s2);
        atomicAdd(&sums[128 + 2 * tid + 1], s3);
    }
    __syncthreads();
}

__global__ __launch_bounds__(512) void mega(MegaParams P) {
    cg::grid_group grid = cg::this_grid();
    const int tid = threadIdx.x;
    const int bid = blockIdx.x;
    const int G = gridDim.x;
    const int gt = bid * 512 + tid;
    const int GT = G * 512;
    const int lane = tid & 63;
    const int w = tid >> 6;
    const int lm = lane & 15, lk = lane >> 4;

    __shared__ __align__(16) unsigned char SMraw[35840];
    ushortT* S = (ushortT*)SMraw;                   // 17408 shorts (34816 B)
    float* sc = (float*)(SMraw + 34816);            // 128
    float* sh = sc + 128;                           // 128
    int* si = (int*)SMraw;                          // scan overlay (512 ints)
    float* lf = (float*)SMraw;                      // stats overlay (2048 floats)

    const int nper = (P.N + 7) / 8;
    const int nbk = (P.N + 511) >> 9;               // 512-wide scan chunks

    // ---------- P1: weight prep + zero cnt/stats ----------
    for (int i = gt; i < 32768; i += GT) {
        int n = i >> 8, k = i & 255;
        P.Wt0[i] = f2bf(P.W0[k * 128 + n]);
        P.WtP[i] = f2bf(P.pW[k * 128 + n]);
    }
    for (int i = gt; i < 16384; i += GT) { int n = i >> 7, k = i & 127; P.Wt1[i] = f2bf(P.W1[k * 128 + n]); }
    for (int i = gt; i < 6144; i += GT)  { int n = i >> 7, k = i & 127; P.WtH[i] = (n < OUT_DIM) ? f2bf(P.hW[k * OUT_DIM + n]) : (ushortT)0; }
    for (int i = gt; i < P.N; i += GT) P.cnt[i] = 0;
    for (int i = gt; i < 512; i += GT) P.stats[i] = 0.f;
    __threadfence();
    grid.sync();

    // ---------- P2: degree count (XCD-partitioned atomics) ----------
    {
        int xcd = bid & 7, nchunk = G >> 3, chunk = bid >> 3;
        int csz = (P.E + nchunk - 1) / nchunk;
        int beg = chunk * csz, end = min(P.E, beg + csz);
        for (int e = beg + tid; e < end; e += 512) {
            int c = P.ei[P.E + e];
            if (c / nper == xcd) atomicAdd(&P.cnt[c], 1);
        }
    }
    __threadfence();
    grid.sync();

    // ---------- P3: chunk sums (+dis) ----------
    for (int c = bid; c < nbk; c += G) {
        int i = c * 512 + tid;
        int cv = (i < P.N) ? P.cnt[i] : -1;
        int v = (i < P.N) ? cv + 1 : 0;                 // +1 self record
        if (i < P.N) P.dis[i] = rsqrtf((float)cv + 2.0f);
        si[tid] = v;
        __syncthreads();
        for (int o = 256; o > 0; o >>= 1) {
            if (tid < o) si[tid] += si[tid + o];
            __syncthreads();
        }
        if (tid == 0) P.bsum[c] = si[0];
        __syncthreads();
    }
    __threadfence();
    grid.sync();

    // ---------- P4: scan chunk sums (block 0) ----------
    if (bid == 0) {
        int v = (tid < nbk) ? P.bsum[tid] : 0;
        si[tid] = v;
        __syncthreads();
        for (int o = 1; o < 512; o <<= 1) {
            int u = (tid >= o) ? si[tid - o] : 0;
            __syncthreads();
            si[tid] += u;
            __syncthreads();
        }
        if (tid < nbk) P.boff[tid] = si[tid] - v;
        if (tid == 511) P.rowptr[P.N] = si[511];
    }
    __threadfence();
    grid.sync();

    // ---------- P5: final scan -> rowptr/cursor + self records ----------
    for (int c = bid; c < nbk; c += G) {
        int i = c * 512 + tid;
        int v = (i < P.N) ? P.cnt[i] + 1 : 0;
        si[tid] = v;
        __syncthreads();
        for (int o = 1; o < 512; o <<= 1) {
            int u = (tid >= o) ? si[tid - o] : 0;
            __syncthreads();
            si[tid] += u;
            __syncthreads();
        }
        if (i < P.N) {
            int e = P.boff[c] + si[tid] - v;
            P.rowptr[i] = e;
            P.cursor[i] = e + 1;
            float d = P.dis[i];
            int2 r; r.x = i; r.y = f2i(2.0f * d * d);
            P.recs[e] = r;
        }
        __syncthreads();
    }
    __threadfence();
    grid.sync();

    // ---------- P6: fill edge records (XCD-partitioned) ----------
    {
        int xcd = bid & 7, nchunk = G >> 3, chunk = bid >> 3;
        int csz = (P.E + nchunk - 1) / nchunk;
        int beg = chunk * csz, end = min(P.E, beg + csz);
        for (int e = beg + tid; e < end; e += 512) {
            int c = P.ei[P.E + e];
            if (c / nper == xcd) {
                int r = P.ei[e];
                int slot = atomicAdd(&P.cursor[c], 1);
                int2 rec; rec.x = r; rec.y = f2i(P.dis[r] * P.dis[c]);
                P.recs[slot] = rec;
            }
        }
    }
    __threadfence();
    grid.sync();

    // ---------- P7: GEMM0 dual (h = x@W0 -> hb16, proj = x@pW+pb -> projb) ----------
    {
        const int mat = w >> 2;
        const int colbase = (w & 3) * 32;
        const ushortT* Wt = mat ? P.WtP : P.Wt0;
        bf16x8 breg[2][8];
#pragma unroll
        for (int nt = 0; nt < 2; ++nt)
#pragma unroll
            for (int kk = 0; kk < 8; ++kk)
                breg[nt][kk] = *(const bf16x8*)&Wt[(size_t)(colbase + nt * 16 + lm) * IN_DIM + kk * 32 + lk * 8];
        float bb0 = mat ? P.pb[colbase + lm] : 0.f;
        float bb1 = mat ? P.pb[colbase + 16 + lm] : 0.f;
        ushortT* Sa = S;
        ushortT* Sb = S + 8704;
        int ntile = (P.N + 63) >> 6;
        for (int t = bid; t < ntile; t += G) {
            int brow = t << 6;
            __syncthreads();                           // S free from previous tile
            float4 pf[4];
            g0l(P.x, brow, 0, tid, P.N, pf);
            g0w(Sa, tid, pf);
            __syncthreads();
            g0l(P.x, brow, 1, tid, P.N, pf);           // issue chunk1 early
            f32x4 acc[4][2];
#pragma unroll
            for (int mt = 0; mt < 4; ++mt)
#pragma unroll
                for (int nt = 0; nt < 2; ++nt) acc[mt][nt] = (f32x4)0.f;
#pragma unroll
            for (int kk = 0; kk < 4; ++kk) {
                bf16x8 af[4];
#pragma unroll
                for (int mt = 0; mt < 4; ++mt)
                    af[mt] = *(const bf16x8*)&Sa[(mt * 16 + lm) * 136 + kk * 32 + lk * 8];
#pragma unroll
                for (int nt = 0; nt < 2; ++nt)
#pragma unroll
                    for (int mt = 0; mt < 4; ++mt)
                        acc[mt][nt] = __builtin_amdgcn_mfma_f32_16x16x32_bf16(af[mt], breg[nt][kk], acc[mt][nt], 0, 0, 0);
            }
            g0w(Sb, tid, pf);
            __syncthreads();
#pragma unroll
            for (int kk = 0; kk < 4; ++kk) {
                bf16x8 af[4];
#pragma unroll
                for (int mt = 0; mt < 4; ++mt)
                    af[mt] = *(const bf16x8*)&Sb[(mt * 16 + lm) * 136 + kk * 32 + lk * 8];
#pragma unroll
                for (int nt = 0; nt < 2; ++nt)
#pragma unroll
                    for (int mt = 0; mt < 4; ++mt)
                        acc[mt][nt] = __builtin_amdgcn_mfma_f32_16x16x32_bf16(af[mt], breg[nt][4 + kk], acc[mt][nt], 0, 0, 0);
            }
            __syncthreads();                           // reuse S as C
#pragma unroll
            for (int mt = 0; mt < 4; ++mt)
#pragma unroll
                for (int nt = 0; nt < 2; ++nt) {
                    int col = colbase + nt * 16 + lm;
                    float bb = nt ? bb1 : bb0;
#pragma unroll
                    for (int j = 0; j < 4; ++j) {
                        int row = mt * 16 + lk * 4 + j;
                        S[mat * 8704 + row * 136 + col] = f2bf(acc[mt][nt][j] + bb);
                    }
                }
            __syncthreads();
#pragma unroll
            for (int i = 0; i < 4; ++i) {
                int idx = i * 512 + tid;
                int m2 = idx >> 10;
                int rem = idx & 1023;
                int row = rem >> 4, colq = rem & 15;
                int gr = brow + row;
                if (gr < P.N) {
                    uint4 v = *(const uint4*)&S[m2 * 8704 + row * 136 + colq * 8];
                    ushortT* O = m2 ? P.projb : P.hb16;
                    *(uint4*)&O[(size_t)gr * 128 + colq * 8] = v;
                }
            }
        }
    }
    __threadfence();
    grid.sync();

    // ---------- P8: aggregate conv0 ----------
    agg_phase(P.hb16, P.rowptr, P.recs, P.aggb, P.N, bid * 8 + w, G * 8, lane);
    __threadfence();
    grid.sync();

    // ---------- P9: BN stats conv0 ----------
    stats_phase((const unsigned*)P.aggb, P.N * 64, P.stats, gt, GT, tid, lf);
    __threadfence();
    grid.sync();

    // ---------- P10: GEMM1 fused (x1 = relu(bn0(agg))+proj -> x1b; h = x1@W1 -> hb16) ----------
    {
        if (tid < 128) {
            float mean = P.stats[tid] / (float)P.N;
            float var = P.stats[128 + tid] / (float)P.N - mean * mean;
            float inv = rsqrtf(var + EPS);
            float s = P.g0[tid] * inv;
            sc[tid] = s;
            sh[tid] = P.be0[tid] - mean * s;
        }
        __syncthreads();
        const int rh = (w >> 2) * 64;
        const int colbase = (w & 3) * 32;
        bf16x8 breg1[2][4];
#pragma unroll
        for (int nt = 0; nt < 2; ++nt)
#pragma unroll
            for (int ks = 0; ks < 4; ++ks)
                breg1[nt][ks] = *(const bf16x8*)&P.Wt1[(size_t)(colbase + nt * 16 + lm) * H + ks * 32 + lk * 8];
        const uint4* aggb4 = (const uint4*)P.aggb;
        const uint4* projb4 = (const uint4*)P.projb;
        uint4* x1b4 = (uint4*)P.x1b;
        int ntile = (P.N + 127) >> 7;
        for (int t = bid; t < ntile; t += G) {
            int brow = t << 7;
            __syncthreads();
#pragma unroll
            for (int i = 0; i < 4; ++i) {
                int idx = i * 512 + tid;
                int row = idx >> 4, q = idx & 15;
                int gr = brow + row;
                uint4 a = make_uint4(0u, 0u, 0u, 0u), p = a;
                if (gr < P.N) {
                    size_t gx = (size_t)gr * 16 + q;
                    a = aggb4[gx];
                    p = projb4[gx];
                }
                int ch = q * 8;
                float v0 = fmaxf(fmaf(bflo(a.x), sc[ch + 0], sh[ch + 0]), 0.f) + bflo(p.x);
                float v1 = fmaxf(fmaf(bfhi(a.x), sc[ch + 1], sh[ch + 1]), 0.f) + bfhi(p.x);
                float v2 = fmaxf(fmaf(bflo(a.y), sc[ch + 2], sh[ch + 2]), 0.f) + bflo(p.y);
                float v3 = fmaxf(fmaf(bfhi(a.y), sc[ch + 3], sh[ch + 3]), 0.f) + bfhi(p.y);
                float v4 = fmaxf(fmaf(bflo(a.z), sc[ch + 4], sh[ch + 4]), 0.f) + bflo(p.z);
                float v5 = fmaxf(fmaf(bfhi(a.z), sc[ch + 5], sh[ch + 5]), 0.f) + bfhi(p.z);
                float v6 = fmaxf(fmaf(bflo(a.w), sc[ch + 6], sh[ch + 6]), 0.f) + bflo(p.w);
                float v7 = fmaxf(fmaf(bfhi(a.w), sc[ch + 7], sh[ch + 7]), 0.f) + bfhi(p.w);
                uint4 pv;
                pv.x = pk2(v0, v1);
                pv.y = pk2(v2, v3);
                pv.z = pk2(v4, v5);
                pv.w = pk2(v6, v7);
                *(uint4*)&S[row * 136 + q * 8] = pv;
                if (gr < P.N) x1b4[(size_t)gr * 16 + q] = pv;
            }
            __syncthreads();
            f32x4 acc[4][2];
#pragma unroll
            for (int mt = 0; mt < 4; ++mt)
#pragma unroll
                for (int nt = 0; nt < 2; ++nt) acc[mt][nt] = (f32x4)0.f;
#pragma unroll
            for (int ks = 0; ks < 4; ++ks) {
                bf16x8 af[4];
#pragma unroll
                for (int mt = 0; mt < 4; ++mt)
                    af[mt] = *(const bf16x8*)&S[(rh + mt * 16 + lm) * 136 + ks * 32 + lk * 8];
#pragma unroll
                for (int nt = 0; nt < 2; ++nt)
#pragma unroll
                    for (int mt = 0; mt < 4; ++mt)
                        acc[mt][nt] = __builtin_amdgcn_mfma_f32_16x16x32_bf16(af[mt], breg1[nt][ks], acc[mt][nt], 0, 0, 0);
            }
            __syncthreads();
#pragma unroll
            for (int mt = 0; mt < 4; ++mt)
#pragma unroll
                for (int nt = 0; nt < 2; ++nt) {
                    int col = colbase + nt * 16 + lm;
#pragma unroll
                    for (int j = 0; j < 4; ++j) {
                        int row = rh + mt * 16 + lk * 4 + j;
                        S[row * 136 + col] = f2bf(acc[mt][nt][j]);
                    }
                }
            __syncthreads();
#pragma unroll
            for (int i = 0; i < 4; ++i) {
                int idx = i * 512 + tid;
                int row = idx >> 4, colq = idx & 15;
                int gr = brow + row;
                if (gr < P.N) {
                    uint4 v = *(const uint4*)&S[row * 136 + colq * 8];
                    *(uint4*)&P.hb16[(size_t)gr * 128 + colq * 8] = v;
                }
            }
        }
    }
    __threadfence();
    grid.sync();

    // ---------- P11: aggregate conv1 ----------
    agg_phase(P.hb16, P.rowptr, P.recs, P.aggb, P.N, bid * 8 + w, G * 8, lane);
    __threadfence();
    grid.sync();

    // ---------- P12: BN stats conv1 ----------
    stats_phase((const unsigned*)P.aggb, P.N * 64, P.stats + 256, gt, GT, tid, lf);
    __threadfence();
    grid.sync();

    // ---------- P13: head (out = (relu(bn1(agg))+x1) @ hW + hb) ----------
    {
        if (tid < 128) {
            float mean = P.stats[256 + tid] / (float)P.N;
            float var = P.stats[384 + tid] / (float)P.N - mean * mean;
            float inv = rsqrtf(var + EPS);
            float s = P.g1[tid] * inv;
            sc[tid] = s;
            sh[tid] = P.be1[tid] - mean * s;
        }
        ushortT* As = S;
        ushortT* Bs = S + 8704;
        for (int idx = tid; idx < 768; idx += 512) {   // 48 rows x 16 uint4
            int row = idx >> 4, q = idx & 15;
            *(uint4*)&Bs[row * 136 + q * 8] = *(const uint4*)&P.WtH[(size_t)row * H + q * 8 ];
        }
        __syncthreads();
        const uint4* aggb4 = (const uint4*)P.aggb;
        const uint4* x1b4 = (const uint4*)P.x1b;
        int ntile = (P.N + 63) >> 6;
        for (int t = bid; t < ntile; t += G) {
            int brow = t << 6;
            __syncthreads();                           // As free
#pragma unroll
            for (int i = 0; i < 2; ++i) {
                int idx = i * 512 + tid;
                int row = idx >> 4, colq = idx & 15;
                int gr = brow + row;
                uint4 a = make_uint4(0u, 0u, 0u, 0u), xv = a;
                if (gr < P.N) {
                    size_t gx = (size_t)brow * 16 + idx;
                    a = aggb4[gx];
                    xv = x1b4[gx];
                }
                int ch = colq * 8;
                float v0 = fmaxf(fmaf(bflo(a.x), sc[ch + 0], sh[ch + 0]), 0.f) + bflo(xv.x);
                float v1 = fmaxf(fmaf(bfhi(a.x), sc[ch + 1], sh[ch + 1]), 0.f) + bfhi(xv.x);
                float v2 = fmaxf(fmaf(bflo(a.y), sc[ch + 2], sh[ch + 2]), 0.f) + bflo(xv.y);
                float v3 = fmaxf(fmaf(bfhi(a.y), sc[ch + 3], sh[ch + 3]), 0.f) + bfhi(xv.y);
                float v4 = fmaxf(fmaf(bflo(a.z), sc[ch + 4], sh[ch + 4]), 0.f) + bflo(xv.z);
                float v5 = fmaxf(fmaf(bfhi(a.z), sc[ch + 5], sh[ch + 5]), 0.f) + bfhi(xv.z);
                float v6 = fmaxf(fmaf(bflo(a.w), sc[ch + 6], sh[ch + 6]), 0.f) + bflo(xv.w);
                float v7 = fmaxf(fmaf(bfhi(a.w), sc[ch + 7], sh[ch + 7]), 0.f) + bfhi(xv.w);
                uint4 pv;
                pv.x = pk2(v0, v1);
                pv.y = pk2(v2, v3);
                pv.z = pk2(v4, v5);
                pv.w = pk2(v6, v7);
                *(uint4*)&As[row * 136 + colq * 8] = pv;
            }
            __syncthreads();
            for (int task = w; task < 12; task += 8) {
                int strip = task & 3, ct = task >> 2;
                f32x4 acc = (f32x4)0.f;
#pragma unroll
                for (int ks = 0; ks < 4; ++ks) {
                    bf16x8 a = *(const bf16x8*)&As[(strip * 16 + lm) * 136 + ks * 32 + lk * 8];
                    bf16x8 b = *(const bf16x8*)&Bs[(ct * 16 + lm) * 136 + ks * 32 + lk * 8];
                    acc = __builtin_amdgcn_mfma_f32_16x16x32_bf16(a, b, acc, 0, 0, 0);
                }
                int col = ct * 16 + lm;
                if (col < OUT_DIM) {
                    float bbv = P.hb[col];
#pragma unroll
                    for (int j = 0; j < 4; ++j) {
                        int r = brow + strip * 16 + lk * 4 + j;
                        if (r < P.N) P.out[(size_t)r * OUT_DIM + col] = acc[j] + bbv;
                    }
                }
            }
        }
    }
}

// ---------------- launch ----------------

extern "C" void kernel_launch(void* const* d_in, const int* in_sizes, int n_in,
                              void* d_out, int out_size, void* d_ws, size_t ws_size,
                              hipStream_t stream) {
    int N = in_sizes[0] / IN_DIM;
    int E = in_sizes[1] / 2;
    size_t NH = (size_t)N * H;

    MegaParams P;
    P.x   = (const float*)d_in[0];
    P.ei  = (const int*)d_in[1];
    P.W0  = (const float*)d_in[2];
    // d_in[3] = b0: cancels in BatchNorm
    P.g0  = (const float*)d_in[4];
    P.be0 = (const float*)d_in[5];
    P.pW  = (const float*)d_in[6];
    P.pb  = (const float*)d_in[7];
    P.W1  = (const float*)d_in[8];
    // d_in[9] = b1: cancels in BatchNorm
    P.g1  = (const float*)d_in[10];
    P.be1 = (const float*)d_in[11];
    P.hW  = (const float*)d_in[12];
    P.hb  = (const float*)d_in[13];
    P.out = (float*)d_out;
    P.N = N;
    P.E = E;

    // workspace layout (all bf16 intermediates)
    P.hb16   = (ushortT*)d_ws;                 // [N,128]
    P.aggb   = P.hb16 + NH;                    // [N,128]
    P.projb  = P.aggb + NH;                    // [N,128]
    P.x1b    = P.projb + NH;                   // [N,128]
    P.dis    = (float*)(P.x1b + NH);           // [N]
    P.cnt    = (int*)(P.dis + N);              // [N]
    P.rowptr = P.cnt + N;                      // [N+1]
    P.cursor = P.rowptr + (N + 1);             // [N]
    P.recs   = (int2*)(P.cursor + N);          // [E+N]
    P.stats  = (float*)(P.recs + (E + N));     // [512]
    P.Wt0    = (ushortT*)(P.stats + 512);      // [128*256]
    P.WtP    = P.Wt0 + 128 * 256;              // [128*256]
    P.Wt1    = P.WtP + 128 * 256;              // [128*128]
    P.WtH    = P.Wt1 + 128 * 128;              // [48*128]
    P.bsum   = (int*)(P.WtH + 48 * 128);       // [512]
    P.boff   = P.bsum + 512;                   // [512]

    int maxb = 1;
    hipOccupancyMaxActiveBlocksPerMultiprocessor(&maxb, mega, 512, 0);
    int G = maxb * 256;                        // 256 CUs on MI355X
    if (G > 512) G = 512;
    if (G < 8) G = 8;
    G &= ~7;                                   // multiple of 8 for XCD partitioning

    void* args[] = { &P };
    hipLaunchCooperativeKernel(mega, dim3(G), dim3(512), args, 0u, stream);
}

// Round 10
// 316.158 us; speedup vs baseline: 23.7482x; 23.7482x over previous
//
#include <hip/hip_runtime.h>

#define H 128
#define IN_DIM 256
#define OUT_DIM 40
#define EPS 1e-5f

typedef unsigned short ushortT;
typedef __attribute__((ext_vector_type(8))) short bf16x8;
typedef __attribute__((ext_vector_type(4))) float f32x4;

static __device__ __forceinline__ ushortT f2bf(float f) {
    union { float f; unsigned u; } v; v.f = f;
    unsigned r = v.u + 0x7FFF + ((v.u >> 16) & 1);   // RNE
    return (ushortT)(r >> 16);
}
static __device__ __forceinline__ unsigned pk2(float a, float b) {
    return (unsigned)f2bf(a) | ((unsigned)f2bf(b) << 16);
}
static __device__ __forceinline__ float bflo(unsigned v) {
    union { unsigned u; float f; } t; t.u = v << 16; return t.f;
}
static __device__ __forceinline__ float bfhi(unsigned v) {
    union { unsigned u; float f; } t; t.u = v & 0xFFFF0000u; return t.f;
}
static __device__ __forceinline__ float i2f(int v) {
    union { int i; float f; } t; t.i = v; return t.f;
}
static __device__ __forceinline__ int f2i(float v) {
    union { float f; int i; } t; t.f = v; return t.i;
}

// ---------------- weight prep: transpose + bf16 (also zeroes cnt + stats) ----------------

__global__ __launch_bounds__(256) void prep_weights(const float* __restrict__ W0, const float* __restrict__ pW,
                                                    const float* __restrict__ W1, const float* __restrict__ hW,
                                                    ushortT* __restrict__ Wt0, ushortT* __restrict__ WtP,
                                                    ushortT* __restrict__ Wt1, ushortT* __restrict__ WtH,
                                                    int* __restrict__ cnt, float* __restrict__ stats, int N) {
    int i = blockIdx.x * 256 + threadIdx.x;
    if (i < 32768) { int n = i >> 8, k = i & 255; Wt0[i] = f2bf(W0[k * 128 + n]); WtP[i] = f2bf(pW[k * 128 + n]); }
    if (i < 16384) { int n = i >> 7, k = i & 127; Wt1[i] = f2bf(W1[k * 128 + n]); }
    if (i < 6144)  { int n = i >> 7, k = i & 127; WtH[i] = (n < OUT_DIM) ? f2bf(hW[k * OUT_DIM + n]) : (ushortT)0; }
    if (i < N) cnt[i] = 0;
    if (i < 512) stats[i] = 0.f;
}

// ---------------- GEMM0 + degree count in one dispatch ----------------
// blocks [0, gemmBlocks): R8 mgemm0d (dual GEMM, K=256 dbuf, LDS epilogue).
// blocks [gemmBlocks, ...): XCD-partitioned degree count (independent of GEMM).

static __device__ __forceinline__ void g0_loads(const float* __restrict__ X, int brow, int kc,
                                                int tid, int N, float4 pf[4]) {
#pragma unroll
    for (int i = 0; i < 4; ++i) {
        int idx = i * 512 + tid;
        int row = idx >> 5, c4 = idx & 31;
        int gr = brow + row;
        pf[i] = make_float4(0.f, 0.f, 0.f, 0.f);
        if (gr < N) pf[i] = *(const float4*)&X[(size_t)gr * IN_DIM + kc * 128 + c4 * 4];
    }
}
static __device__ __forceinline__ void g0_write(ushortT* __restrict__ Sbuf, int tid, const float4 pf[4]) {
#pragma unroll
    for (int i = 0; i < 4; ++i) {
        int idx = i * 512 + tid;
        int row = idx >> 5, c4 = idx & 31;
        uint2 p;
        p.x = pk2(pf[i].x, pf[i].y);
        p.y = pk2(pf[i].z, pf[i].w);
        *(uint2*)&Sbuf[row * 136 + c4 * 4] = p;
    }
}

__global__ __launch_bounds__(512) void gemm0_count(const float* __restrict__ X,
                                                   const ushortT* __restrict__ Wt0,
                                                   const ushortT* __restrict__ WtP,
                                                   const float* __restrict__ pb,
                                                   ushortT* __restrict__ Oh,
                                                   ushortT* __restrict__ Op,
                                                   const int* __restrict__ ei,
                                                   int* __restrict__ cnt,
                                                   int N, int E, int nper, int gemmBlocks) {
    __shared__ __align__(16) ushortT S2[2][64 * 136];
    int tid = threadIdx.x;

    if (blockIdx.x >= gemmBlocks) {
        // ---- count role ----
        int cbid = blockIdx.x - gemmBlocks;
        int xcd = cbid & 7;
        int nchunk = (gridDim.x - gemmBlocks) >> 3;
        int chunk = cbid >> 3;
        int csz = (E + nchunk - 1) / nchunk;
        int beg = chunk * csz;
        int end = min(E, beg + csz);
        for (int e = beg + tid; e < end; e += 512) {
            int c = ei[E + e];
            if (c / nper == xcd) atomicAdd(&cnt[c], 1);
        }
        return;
    }

    // ---- GEMM role (R8 mgemm0d verbatim) ----
    int brow = blockIdx.x * 64;
    int w = tid >> 6, lane = tid & 63;
    int lm = lane & 15, lk = lane >> 4;
    int mat = w >> 2;
    int colbase = (w & 3) * 32;
    const ushortT* Wt = mat ? WtP : Wt0;

    bf16x8 breg[2][8];
#pragma unroll
    for (int nt = 0; nt < 2; ++nt)
#pragma unroll
        for (int kk = 0; kk < 8; ++kk)
            breg[nt][kk] = *(const bf16x8*)&Wt[(size_t)(colbase + nt * 16 + lm) * IN_DIM + kk * 32 + lk * 8];
    float bb[2];
    bb[0] = mat ? pb[colbase + lm] : 0.f;
    bb[1] = mat ? pb[colbase + 16 + lm] : 0.f;

    float4 pf[4];
    g0_loads(X, brow, 0, tid, N, pf);
    g0_write(S2[0], tid, pf);
    __syncthreads();                                   // buf0 staged
    g0_loads(X, brow, 1, tid, N, pf);                  // issue chunk1 early

    f32x4 acc[4][2];
#pragma unroll
    for (int mt = 0; mt < 4; ++mt)
#pragma unroll
        for (int nt = 0; nt < 2; ++nt) acc[mt][nt] = (f32x4)0.f;

#pragma unroll
    for (int kk = 0; kk < 4; ++kk) {
        bf16x8 af[4];
#pragma unroll
        for (int mt = 0; mt < 4; ++mt)
            af[mt] = *(const bf16x8*)&S2[0][(mt * 16 + lm) * 136 + kk * 32 + lk * 8];
#pragma unroll
        for (int nt = 0; nt < 2; ++nt)
#pragma unroll
            for (int mt = 0; mt < 4; ++mt)
                acc[mt][nt] = __builtin_amdgcn_mfma_f32_16x16x32_bf16(af[mt], breg[nt][kk], acc[mt][nt], 0, 0, 0);
    }
    g0_write(S2[1], tid, pf);
    __syncthreads();                                   // buf1 staged
#pragma unroll
    for (int kk = 0; kk < 4; ++kk) {
        bf16x8 af[4];
#pragma unroll
        for (int mt = 0; mt < 4; ++mt)
            af[mt] = *(const bf16x8*)&S2[1][(mt * 16 + lm) * 136 + kk * 32 + lk * 8];
#pragma unroll
        for (int nt = 0; nt < 2; ++nt)
#pragma unroll
            for (int mt = 0; mt < 4; ++mt)
                acc[mt][nt] = __builtin_amdgcn_mfma_f32_16x16x32_bf16(af[mt], breg[nt][4 + kk], acc[mt][nt], 0, 0, 0);
    }
    __syncthreads();                                   // all LDS reads done; reuse as C
#pragma unroll
    for (int mt = 0; mt < 4; ++mt)
#pragma unroll
        for (int nt = 0; nt < 2; ++nt) {
            int col = colbase + nt * 16 + lm;
#pragma unroll
            for (int j = 0; j < 4; ++j) {
                int row = mt * 16 + lk * 4 + j;
                S2[mat][row * 136 + col] = f2bf(acc[mt][nt][j] + bb[nt]);
            }
        }
    __syncthreads();
#pragma unroll
    for (int i = 0; i < 4; ++i) {
        int idx = i * 512 + tid;
        int m2 = idx >> 10;
        int rem = idx & 1023;
        int row = rem >> 4, colq = rem & 15;
        int gr = brow + row;
        if (gr < N) {
            uint4 v = *(const uint4*)&S2[m2][row * 136 + colq * 8];
            ushortT* O = m2 ? Op : Oh;
            *(uint4*)&O[(size_t)gr * 128 + colq * 8] = v;
        }
    }
}

// ---------------- scan hierarchy (R8) ----------------

__global__ __launch_bounds__(256) void scan_block_sum(const int* __restrict__ cnt, int* __restrict__ bsum,
                                                      float* __restrict__ dis, int N) {
    __shared__ int s[256];
    int i = blockIdx.x * 256 + threadIdx.x;
    int c = (i < N) ? cnt[i] : -1;
    int v = (i < N) ? c + 1 : 0;
    if (i < N) dis[i] = rsqrtf((float)c + 2.0f);
    s[threadIdx.x] = v;
    __syncthreads();
    for (int o = 128; o > 0; o >>= 1) {
        if (threadIdx.x < o) s[threadIdx.x] += s[threadIdx.x + o];
        __syncthreads();
    }
    if (threadIdx.x == 0) bsum[blockIdx.x] = s[0];
}

__global__ void scan_tops(const int* __restrict__ bsum, int* __restrict__ boff, int* __restrict__ rowptrN, int nb) {
    __shared__ int s[256];
    int t = threadIdx.x;
    int v = (t < nb) ? bsum[t] : 0;
    s[t] = v;
    __syncthreads();
    for (int o = 1; o < 256; o <<= 1) {
        int u = (t >= o) ? s[t - o] : 0;
        __syncthreads();
        s[t] += u;
        __syncthreads();
    }
    if (t < nb) boff[t] = s[t] - v;
    if (t == 255) *rowptrN = s[255];
}

__global__ __launch_bounds__(256) void scan_final(const int* __restrict__ cnt, const int* __restrict__ boff,
                                                  const float* __restrict__ dis,
                                                  int* __restrict__ rowptr, int* __restrict__ cursor,
                                                  int2* __restrict__ recs, int N) {
    __shared__ int s[256];
    int t = threadIdx.x;
    int i = blockIdx.x * 256 + t;
    int v = (i < N) ? cnt[i] + 1 : 0;
    s[t] = v;
    __syncthreads();
    for (int o = 1; o < 256; o <<= 1) {
        int u = (t >= o) ? s[t - o] : 0;
        __syncthreads();
        s[t] += u;
        __syncthreads();
    }
    if (i < N) {
        int e = boff[blockIdx.x] + s[t] - v;
        rowptr[i] = e;
        cursor[i] = e + 1;                    // slot e holds the self record
        float d = dis[i];
        int2 r; r.x = i; r.y = f2i(2.0f * d * d);
        recs[e] = r;
    }
}

// XCD-partitioned fill; writes (src, dis[src]*dis[dst]) records
__global__ __launch_bounds__(256) void fill_xcd(const int* __restrict__ ei, int E, int nper,
                                                const float* __restrict__ dis,
                                                int* __restrict__ cursor, int2* __restrict__ recs) {
    int xcd = blockIdx.x & 7;
    int nchunk = gridDim.x >> 3;
    int chunk = blockIdx.x >> 3;
    int csz = (E + nchunk - 1) / nchunk;
    int beg = chunk * csz;
    int end = min(E, beg + csz);
    for (int e = beg + (int)threadIdx.x; e < end; e += 256) {
        int c = ei[E + e];
        if (c / nper == xcd) {
            int r = ei[e];
            int slot = atomicAdd(&cursor[c], 1);
            int2 rec; rec.x = r; rec.y = f2i(dis[r] * dis[c]);
            recs[slot] = rec;
        }
    }
}

// ---------------- aggregation + fused BN stats ----------------
// grid-stride persistent: 2048 blocks x 4 waves, one node per wave per iter.
// half 0 accumulates channel sums, half 1 channel sum-of-squares (of the bf16-rounded
// values, matching R8's stats_bf numerics). Block-level LDS reduce + one atomic flush.

__global__ __launch_bounds__(256) void aggregate_stats(const ushortT* __restrict__ h,
                                                       const int* __restrict__ rowptr,
                                                       const int2* __restrict__ recs,
                                                       ushortT* __restrict__ aggb,
                                                       float* __restrict__ stats, int N) {
    __shared__ float sumL[128], sqL[128];
    int tid = threadIdx.x;
    if (tid < 128) { sumL[tid] = 0.f; sqL[tid] = 0.f; }
    __syncthreads();

    int wv = tid >> 6, lane = tid & 63;
    int half = lane >> 5, cl = lane & 31;
    const uint2* h2 = (const uint2*)h;           // 8B units; row stride 32
    float s0 = 0.f, s1 = 0.f, s2 = 0.f, s3 = 0.f;   // sums (half0) / sumsq (half1)

    int stride = gridDim.x * 4;
    for (int n = blockIdx.x * 4 + wv; n < N; n += stride) {
        int beg = rowptr[n], end = rowptr[n + 1];
        float a0 = 0.f, a1 = 0.f, a2 = 0.f, a3 = 0.f;
        float b0 = 0.f, b1 = 0.f, b2 = 0.f, b3 = 0.f;
        int idx = beg + half;
        for (; idx + 2 < end; idx += 4) {
            int2 r0 = recs[idx];
            int2 r1 = recs[idx + 2];
            uint2 v0 = h2[(size_t)r0.x * 32 + cl];
            uint2 v1 = h2[(size_t)r1.x * 32 + cl];
            float n0 = i2f(r0.y), n1 = i2f(r1.y);
            a0 = fmaf(n0, bflo(v0.x), a0); a1 = fmaf(n0, bfhi(v0.x), a1);
            a2 = fmaf(n0, bflo(v0.y), a2); a3 = fmaf(n0, bfhi(v0.y), a3);
            b0 = fmaf(n1, bflo(v1.x), b0); b1 = fmaf(n1, bfhi(v1.x), b1);
            b2 = fmaf(n1, bflo(v1.y), b2); b3 = fmaf(n1, bfhi(v1.y), b3);
        }
        if (idx < end) {
            int2 r0 = recs[idx];
            uint2 v0 = h2[(size_t)r0.x * 32 + cl];
            float n0 = i2f(r0.y);
            a0 = fmaf(n0, bflo(v0.x), a0); a1 = fmaf(n0, bfhi(v0.x), a1);
            a2 = fmaf(n0, bflo(v0.y), a2); a3 = fmaf(n0, bfhi(v0.y), a3);
        }
        a0 += b0; a1 += b1; a2 += b2; a3 += b3;
        a0 += __shfl_xor(a0, 32);
        a1 += __shfl_xor(a1, 32);
        a2 += __shfl_xor(a2, 32);
        a3 += __shfl_xor(a3, 32);
        unsigned ox = pk2(a0, a1);
        unsigned oy = pk2(a2, a3);
        if (half == 0) {
            uint2 o; o.x = ox; o.y = oy;
            ((uint2*)aggb)[(size_t)n * 32 + cl] = o;
        }
        float r0 = bflo(ox), r1 = bfhi(ox), r2 = bflo(oy), r3 = bfhi(oy);
        if (half == 0) {
            s0 += r0; s1 += r1; s2 += r2; s3 += r3;
        } else {
            s0 = fmaf(r0, r0, s0); s1 = fmaf(r1, r1, s1);
            s2 = fmaf(r2, r2, s2); s3 = fmaf(r3, r3, s3);
        }
    }

    float* dst = half ? sqL : sumL;
    atomicAdd(&dst[4 * cl + 0], s0);
    atomicAdd(&dst[4 * cl + 1], s1);
    atomicAdd(&dst[4 * cl + 2], s2);
    atomicAdd(&dst[4 * cl + 3], s3);
    __syncthreads();
    if (tid < 128) atomicAdd(&stats[tid], sumL[tid]);
    else atomicAdd(&stats[tid], sqL[tid - 128]);       // stats[128..255] = sumsq
}

// ---------------- GEMM1 fused: x1 = relu(bn0(agg)) + proj (written out), h = x1 @ W1, LDS epilogue ----------------

__global__ __launch_bounds__(512) void mgemm1_fused(const uint4* __restrict__ aggb,
                                                    const uint4* __restrict__ projb,
                                                    const float* __restrict__ stats,
                                                    const float* __restrict__ g,
                                                    const float* __restrict__ be,
                                                    const ushortT* __restrict__ Wt1,
                                                    ushortT* __restrict__ O,
                                                    uint4* __restrict__ x1b,
                                                    int N) {
    __shared__ __align__(16) ushortT S[17408];
    __shared__ float sc[128], sh[128];
    int tid = threadIdx.x;
    int brow = blockIdx.x * 128;

    if (tid < 128) {
        float mean = stats[tid] / (float)N;
        float var = stats[128 + tid] / (float)N - mean * mean;
        float inv = rsqrtf(var + EPS);
        float s = g[tid] * inv;
        sc[tid] = s;
        sh[tid] = be[tid] - mean * s;
    }
    __syncthreads();

#pragma unroll
    for (int i = 0; i < 4; ++i) {
        int idx = i * 512 + tid;
        int row = idx >> 4, q = idx & 15;
        int gr = brow + row;
        uint4 a = make_uint4(0u, 0u, 0u, 0u), p = a;
        if (gr < N) {
            size_t gidx = (size_t)gr * 16 + q;
            a = aggb[gidx];
            p = projb[gidx];
        }
        int ch = q * 8;
        float v0 = fmaxf(fmaf(bflo(a.x), sc[ch + 0], sh[ch + 0]), 0.f) + bflo(p.x);
        float v1 = fmaxf(fmaf(bfhi(a.x), sc[ch + 1], sh[ch + 1]), 0.f) + bfhi(p.x);
        float v2 = fmaxf(fmaf(bflo(a.y), sc[ch + 2], sh[ch + 2]), 0.f) + bflo(p.y);
        float v3 = fmaxf(fmaf(bfhi(a.y), sc[ch + 3], sh[ch + 3]), 0.f) + bfhi(p.y);
        float v4 = fmaxf(fmaf(bflo(a.z), sc[ch + 4], sh[ch + 4]), 0.f) + bflo(p.z);
        float v5 = fmaxf(fmaf(bfhi(a.z), sc[ch + 5], sh[ch + 5]), 0.f) + bfhi(p.z);
        float v6 = fmaxf(fmaf(bflo(a.w), sc[ch + 6], sh[ch + 6]), 0.f) + bflo(p.w);
        float v7 = fmaxf(fmaf(bfhi(a.w), sc[ch + 7], sh[ch + 7]), 0.f) + bfhi(p.w);
        uint4 pv;
        pv.x = pk2(v0, v1);
        pv.y = pk2(v2, v3);
        pv.z = pk2(v4, v5);
        pv.w = pk2(v6, v7);
        *(uint4*)&S[row * 136 + q * 8] = pv;
        if (gr < N) x1b[(size_t)gr * 16 + q] = pv;
    }
    __syncthreads();

    int w = tid >> 6, lane = tid & 63;
    int lm = lane & 15, lk = lane >> 4;
    int rh = (w >> 2) * 64;
    int colbase = (w & 3) * 32;

    bf16x8 breg[2][4];
#pragma unroll
    for (int nt = 0; nt < 2; ++nt)
#pragma unroll
        for (int ks = 0; ks < 4; ++ks)
            breg[nt][ks] = *(const bf16x8*)&Wt1[(size_t)(colbase + nt * 16 + lm) * H + ks * 32 + lk * 8];

    f32x4 acc[4][2];
#pragma unroll
    for (int mt = 0; mt < 4; ++mt)
#pragma unroll
        for (int nt = 0; nt < 2; ++nt) acc[mt][nt] = (f32x4)0.f;

#pragma unroll
    for (int ks = 0; ks < 4; ++ks) {
        bf16x8 af[4];
#pragma unroll
        for (int mt = 0; mt < 4; ++mt)
            af[mt] = *(const bf16x8*)&S[(rh + mt * 16 + lm) * 136 + ks * 32 + lk * 8];
#pragma unroll
        for (int nt = 0; nt < 2; ++nt)
#pragma unroll
            for (int mt = 0; mt < 4; ++mt)
                acc[mt][nt] = __builtin_amdgcn_mfma_f32_16x16x32_bf16(af[mt], breg[nt][ks], acc[mt][nt], 0, 0, 0);
    }

    __syncthreads();
#pragma unroll
    for (int mt = 0; mt < 4; ++mt)
#pragma unroll
        for (int nt = 0; nt < 2; ++nt) {
            int col = colbase + nt * 16 + lm;
#pragma unroll
            for (int j = 0; j < 4; ++j) {
                int row = rh + mt * 16 + lk * 4 + j;
                S[row * 136 + col] = f2bf(acc[mt][nt][j]);
            }
        }
    __syncthreads();
#pragma unroll
    for (int i = 0; i < 4; ++i) {
        int idx = i * 512 + tid;
        int row = idx >> 4, colq = idx & 15;
        int gr = brow + row;
        if (gr < N) {
            uint4 v = *(const uint4*)&S[row * 136 + colq * 8];
            *(uint4*)&O[(size_t)gr * 128 + colq * 8] = v;
        }
    }
}

// ---------------- head: out = (relu(bn1(agg)) + x1) @ hW + hb, x2 inline ----------------

__global__ __launch_bounds__(256) void head_fused(const uint4* __restrict__ aggb,
                                                  const uint4* __restrict__ x1b,
                                                  const float* __restrict__ stats,
                                                  const float* __restrict__ g,
                                                  const float* __restrict__ be,
                                                  const ushortT* __restrict__ WtH,
                                                  const float* __restrict__ hb,
                                                  float* __restrict__ out, int N) {
    __shared__ __align__(16) ushortT As[64][136];
    __shared__ __align__(16) ushortT Bs[48][136];
    __shared__ float sc[128], sh[128];

    int tid = threadIdx.x;
    int brow = blockIdx.x * 64;
    int w = tid >> 6, lane = tid & 63;
    int lm = lane & 15, lk = lane >> 4;

    if (tid < 128) {
        float mean = stats[tid] / (float)N;
        float var = stats[128 + tid] / (float)N - mean * mean;
        float inv = rsqrtf(var + EPS);
        float s = g[tid] * inv;
        sc[tid] = s;
        sh[tid] = be[tid] - mean * s;
    }
    if (tid < 192) {
        int row = tid >> 2, q = tid & 3;
        const uint4* src = (const uint4*)&WtH[(size_t)row * H + q * 32];
        uint4 a = src[0], b = src[1], c = src[2], d = src[3];
        uint4* dst = (uint4*)&Bs[row][q * 32];
        dst[0] = a; dst[1] = b; dst[2] = c; dst[3] = d;
    }
    __syncthreads();
#pragma unroll
    for (int k = 0; k < 4; ++k) {
        int idx = k * 256 + tid;
        int row = idx >> 4, colq = idx & 15;
        int gr = brow + row;
        uint4 a = make_uint4(0u, 0u, 0u, 0u), x = a;
        if (gr < N) {
            size_t gidx = (size_t)brow * 16 + idx;
            a = aggb[gidx];
            x = x1b[gidx];
        }
        int ch = colq * 8;
        float v0 = fmaxf(fmaf(bflo(a.x), sc[ch + 0], sh[ch + 0]), 0.f) + bflo(x.x);
        float v1 = fmaxf(fmaf(bfhi(a.x), sc[ch + 1], sh[ch + 1]), 0.f) + bfhi(x.x);
        float v2 = fmaxf(fmaf(bflo(a.y), sc[ch + 2], sh[ch + 2]), 0.f) + bflo(x.y);
        float v3 = fmaxf(fmaf(bfhi(a.y), sc[ch + 3], sh[ch + 3]), 0.f) + bfhi(x.y);
        float v4 = fmaxf(fmaf(bflo(a.z), sc[ch + 4], sh[ch + 4]), 0.f) + bflo(x.z);
        float v5 = fmaxf(fmaf(bfhi(a.z), sc[ch + 5], sh[ch + 5]), 0.f) + bfhi(x.z);
        float v6 = fmaxf(fmaf(bflo(a.w), sc[ch + 6], sh[ch + 6]), 0.f) + bflo(x.w);
        float v7 = fmaxf(fmaf(bfhi(a.w), sc[ch + 7], sh[ch + 7]), 0.f) + bfhi(x.w);
        uint4 pv;
        pv.x = pk2(v0, v1);
        pv.y = pk2(v2, v3);
        pv.z = pk2(v4, v5);
        pv.w = pk2(v6, v7);
        *(uint4*)&As[row][colq * 8] = pv;
    }
    __syncthreads();

    f32x4 acc[3];
#pragma unroll
    for (int nt = 0; nt < 3; ++nt) acc[nt] = (f32x4)0.f;
#pragma unroll
    for (int ks = 0; ks < 4; ++ks) {
        bf16x8 a = *(const bf16x8*)&As[w * 16 + lm][ks * 32 + lk * 8];
#pragma unroll
        for (int nt = 0; nt < 3; ++nt) {
            bf16x8 b = *(const bf16x8*)&Bs[nt * 16 + lm][ks * 32 + lk * 8];
            acc[nt] = __builtin_amdgcn_mfma_f32_16x16x32_bf16(a, b, acc[nt], 0, 0, 0);
        }
    }
#pragma unroll
    for (int nt = 0; nt < 3; ++nt) {
        int col = nt * 16 + lm;
        if (col < OUT_DIM) {
            float bbv = hb[col];
#pragma unroll
            for (int j = 0; j < 4; ++j) {
                int r = brow + w * 16 + lk * 4 + j;
                if (r < N) out[(size_t)r * OUT_DIM + col] = acc[nt][j] + bbv;
            }
        }
    }
}

// ---------------- launch ----------------

extern "C" void kernel_launch(void* const* d_in, const int* in_sizes, int n_in,
                              void* d_out, int out_size, void* d_ws, size_t ws_size,
                              hipStream_t stream) {
    const float* x   = (const float*)d_in[0];
    const int*   ei  = (const int*)d_in[1];
    const float* W0  = (const float*)d_in[2];
    // d_in[3] = b0: cancels in BatchNorm
    const float* g0  = (const float*)d_in[4];
    const float* be0 = (const float*)d_in[5];
    const float* pW  = (const float*)d_in[6];
    const float* pb  = (const float*)d_in[7];
    const float* W1  = (const float*)d_in[8];
    // d_in[9] = b1: cancels in BatchNorm
    const float* g1  = (const float*)d_in[10];
    const float* be1 = (const float*)d_in[11];
    const float* hW  = (const float*)d_in[12];
    const float* hb  = (const float*)d_in[13];
    float* out = (float*)d_out;

    int N = in_sizes[0] / IN_DIM;
    int E = in_sizes[1] / 2;
    size_t NH = (size_t)N * H;

    // workspace layout (all bf16 intermediates)
    ushortT* hb16   = (ushortT*)d_ws;            // [N,128] conv input h
    ushortT* aggb   = hb16 + NH;                 // [N,128] aggregated
    ushortT* projb  = aggb + NH;                 // [N,128] proj (block0)
    ushortT* x1b    = projb + NH;                // [N,128] x1
    float*   dis    = (float*)(x1b + NH);        // [N]
    int*     cnt    = (int*)(dis + N);           // [N]
    int*     rowptr = cnt + N;                   // [N+1]
    int*     cursor = rowptr + (N + 1);          // [N]
    int2*    recs   = (int2*)(cursor + N);       // [E+N] (8B-aligned)
    float*   stats  = (float*)(recs + (E + N));  // [512]: conv0 then conv1
    ushortT* Wt0    = (ushortT*)(stats + 512);   // [128*256]
    ushortT* WtP    = Wt0 + 128 * 256;           // [128*256]
    ushortT* Wt1    = WtP + 128 * 256;           // [128*128]
    ushortT* WtH    = Wt1 + 128 * 128;           // [48*128]
    int*     bsum   = (int*)(WtH + 48 * 128);    // [256]
    int*     boff   = bsum + 256;                // [256]
    float*   stats0 = stats;
    float*   stats1 = stats + 256;

    int nb = (N + 255) / 256;
    int g64 = (N + 63) / 64;
    int g128 = (N + 127) / 128;
    int nper = (N + 7) / 8;
    const int CNT_BLOCKS = 1024;                 // count role blocks (multiple of 8)

    // prep (weights + zero cnt/stats)
    prep_weights<<<196, 256, 0, stream>>>(W0, pW, W1, hW, Wt0, WtP, Wt1, WtH, cnt, stats, N);

    // GEMM0 (dual) + degree count in one dispatch
    gemm0_count<<<g64 + CNT_BLOCKS, 512, 0, stream>>>(x, Wt0, WtP, pb, hb16, projb,
                                                      ei, cnt, N, E, nper, g64);

    // CSR offsets + records
    scan_block_sum<<<nb, 256, 0, stream>>>(cnt, bsum, dis, N);
    scan_tops<<<1, 256, 0, stream>>>(bsum, boff, &rowptr[N], nb);
    scan_final<<<nb, 256, 0, stream>>>(cnt, boff, dis, rowptr, cursor, recs, N);
    fill_xcd<<<2048, 256, 0, stream>>>(ei, E, nper, dis, cursor, recs);

    // block 0: aggregate + BN stats fused
    aggregate_stats<<<2048, 256, 0, stream>>>(hb16, rowptr, recs, aggb, stats0, N);

    // block 1 (x1 = relu(bn0(agg)) + proj fused into GEMM1's staging; x1 also written for head)
    mgemm1_fused<<<g128, 512, 0, stream>>>((const uint4*)aggb, (const uint4*)projb, stats0, g0, be0,
                                           Wt1, hb16, (uint4*)x1b, N);
    aggregate_stats<<<2048, 256, 0, stream>>>(hb16, rowptr, recs, aggb, stats1, N);

    // head (x2 computed inline)
    head_fused<<<g64, 256, 0, stream>>>((const uint4*)aggb, (const uint4*)x1b, stats1, g1, be1,
                                        WtH, hb, out, N);
}

// Round 11
// 244.667 us; speedup vs baseline: 30.6873x; 1.2922x over previous
//
#include <hip/hip_runtime.h>

#define H 128
#define IN_DIM 256
#define OUT_DIM 40
#define EPS 1e-5f

typedef unsigned short ushortT;
typedef __attribute__((ext_vector_type(8))) short bf16x8;
typedef __attribute__((ext_vector_type(4))) float f32x4;

static __device__ __forceinline__ ushortT f2bf(float f) {
    union { float f; unsigned u; } v; v.f = f;
    unsigned r = v.u + 0x7FFF + ((v.u >> 16) & 1);   // RNE
    return (ushortT)(r >> 16);
}
static __device__ __forceinline__ unsigned pk2(float a, float b) {
    return (unsigned)f2bf(a) | ((unsigned)f2bf(b) << 16);
}
static __device__ __forceinline__ float bflo(unsigned v) {
    union { unsigned u; float f; } t; t.u = v << 16; return t.f;
}
static __device__ __forceinline__ float bfhi(unsigned v) {
    union { unsigned u; float f; } t; t.u = v & 0xFFFF0000u; return t.f;
}
static __device__ __forceinline__ float i2f(int v) {
    union { int i; float f; } t; t.i = v; return t.f;
}
static __device__ __forceinline__ int f2i(float v) {
    union { float f; int i; } t; t.f = v; return t.i;
}

// ---------------- weight prep: transpose + bf16 (also zeroes cnt + stats) ----------------

__global__ __launch_bounds__(256) void prep_weights(const float* __restrict__ W0, const float* __restrict__ pW,
                                                    const float* __restrict__ W1, const float* __restrict__ hW,
                                                    ushortT* __restrict__ Wt0, ushortT* __restrict__ WtP,
                                                    ushortT* __restrict__ Wt1, ushortT* __restrict__ WtH,
                                                    int* __restrict__ cnt, float* __restrict__ stats, int N) {
    int i = blockIdx.x * 256 + threadIdx.x;
    if (i < 32768) { int n = i >> 8, k = i & 255; Wt0[i] = f2bf(W0[k * 128 + n]); WtP[i] = f2bf(pW[k * 128 + n]); }
    if (i < 16384) { int n = i >> 7, k = i & 127; Wt1[i] = f2bf(W1[k * 128 + n]); }
    if (i < 6144)  { int n = i >> 7, k = i & 127; WtH[i] = (n < OUT_DIM) ? f2bf(hW[k * OUT_DIM + n]) : (ushortT)0; }
    if (i < N) cnt[i] = 0;
    if (i < 512) stats[i] = 0.f;
}

// ---------------- GEMM0 + degree count in one dispatch ----------------
// blocks [0, gemmBlocks): R8 mgemm0d (dual GEMM, K=256 dbuf, LDS epilogue).
// blocks [gemmBlocks, ...): XCD-partitioned degree count (independent of GEMM).

static __device__ __forceinline__ void g0_loads(const float* __restrict__ X, int brow, int kc,
                                                int tid, int N, float4 pf[4]) {
#pragma unroll
    for (int i = 0; i < 4; ++i) {
        int idx = i * 512 + tid;
        int row = idx >> 5, c4 = idx & 31;
        int gr = brow + row;
        pf[i] = make_float4(0.f, 0.f, 0.f, 0.f);
        if (gr < N) pf[i] = *(const float4*)&X[(size_t)gr * IN_DIM + kc * 128 + c4 * 4];
    }
}
static __device__ __forceinline__ void g0_write(ushortT* __restrict__ Sbuf, int tid, const float4 pf[4]) {
#pragma unroll
    for (int i = 0; i < 4; ++i) {
        int idx = i * 512 + tid;
        int row = idx >> 5, c4 = idx & 31;
        uint2 p;
        p.x = pk2(pf[i].x, pf[i].y);
        p.y = pk2(pf[i].z, pf[i].w);
        *(uint2*)&Sbuf[row * 136 + c4 * 4] = p;
    }
}

__global__ __launch_bounds__(512) void gemm0_count(const float* __restrict__ X,
                                                   const ushortT* __restrict__ Wt0,
                                                   const ushortT* __restrict__ WtP,
                                                   const float* __restrict__ pb,
                                                   ushortT* __restrict__ Oh,
                                                   ushortT* __restrict__ Op,
                                                   const int* __restrict__ ei,
                                                   int* __restrict__ cnt,
                                                   int N, int E, int nper, int gemmBlocks) {
    __shared__ __align__(16) ushortT S2[2][64 * 136];
    int tid = threadIdx.x;

    if (blockIdx.x >= gemmBlocks) {
        // ---- count role ----
        int cbid = blockIdx.x - gemmBlocks;
        int xcd = cbid & 7;
        int nchunk = (gridDim.x - gemmBlocks) >> 3;
        int chunk = cbid >> 3;
        int csz = (E + nchunk - 1) / nchunk;
        int beg = chunk * csz;
        int end = min(E, beg + csz);
        for (int e = beg + tid; e < end; e += 512) {
            int c = ei[E + e];
            if (c / nper == xcd) atomicAdd(&cnt[c], 1);
        }
        return;
    }

    // ---- GEMM role (R8 mgemm0d verbatim) ----
    int brow = blockIdx.x * 64;
    int w = tid >> 6, lane = tid & 63;
    int lm = lane & 15, lk = lane >> 4;
    int mat = w >> 2;
    int colbase = (w & 3) * 32;
    const ushortT* Wt = mat ? WtP : Wt0;

    bf16x8 breg[2][8];
#pragma unroll
    for (int nt = 0; nt < 2; ++nt)
#pragma unroll
        for (int kk = 0; kk < 8; ++kk)
            breg[nt][kk] = *(const bf16x8*)&Wt[(size_t)(colbase + nt * 16 + lm) * IN_DIM + kk * 32 + lk * 8];
    float bb[2];
    bb[0] = mat ? pb[colbase + lm] : 0.f;
    bb[1] = mat ? pb[colbase + 16 + lm] : 0.f;

    float4 pf[4];
    g0_loads(X, brow, 0, tid, N, pf);
    g0_write(S2[0], tid, pf);
    __syncthreads();                                   // buf0 staged
    g0_loads(X, brow, 1, tid, N, pf);                  // issue chunk1 early

    f32x4 acc[4][2];
#pragma unroll
    for (int mt = 0; mt < 4; ++mt)
#pragma unroll
        for (int nt = 0; nt < 2; ++nt) acc[mt][nt] = (f32x4)0.f;

#pragma unroll
    for (int kk = 0; kk < 4; ++kk) {
        bf16x8 af[4];
#pragma unroll
        for (int mt = 0; mt < 4; ++mt)
            af[mt] = *(const bf16x8*)&S2[0][(mt * 16 + lm) * 136 + kk * 32 + lk * 8];
#pragma unroll
        for (int nt = 0; nt < 2; ++nt)
#pragma unroll
            for (int mt = 0; mt < 4; ++mt)
                acc[mt][nt] = __builtin_amdgcn_mfma_f32_16x16x32_bf16(af[mt], breg[nt][kk], acc[mt][nt], 0, 0, 0);
    }
    g0_write(S2[1], tid, pf);
    __syncthreads();                                   // buf1 staged
#pragma unroll
    for (int kk = 0; kk < 4; ++kk) {
        bf16x8 af[4];
#pragma unroll
        for (int mt = 0; mt < 4; ++mt)
            af[mt] = *(const bf16x8*)&S2[1][(mt * 16 + lm) * 136 + kk * 32 + lk * 8];
#pragma unroll
        for (int nt = 0; nt < 2; ++nt)
#pragma unroll
            for (int mt = 0; mt < 4; ++mt)
                acc[mt][nt] = __builtin_amdgcn_mfma_f32_16x16x32_bf16(af[mt], breg[nt][4 + kk], acc[mt][nt], 0, 0, 0);
    }
    __syncthreads();                                   // all LDS reads done; reuse as C
#pragma unroll
    for (int mt = 0; mt < 4; ++mt)
#pragma unroll
        for (int nt = 0; nt < 2; ++nt) {
            int col = colbase + nt * 16 + lm;
#pragma unroll
            for (int j = 0; j < 4; ++j) {
                int row = mt * 16 + lk * 4 + j;
                S2[mat][row * 136 + col] = f2bf(acc[mt][nt][j] + bb[nt]);
            }
        }
    __syncthreads();
#pragma unroll
    for (int i = 0; i < 4; ++i) {
        int idx = i * 512 + tid;
        int m2 = idx >> 10;
        int rem = idx & 1023;
        int row = rem >> 4, colq = rem & 15;
        int gr = brow + row;
        if (gr < N) {
            uint4 v = *(const uint4*)&S2[m2][row * 136 + colq * 8];
            ushortT* O = m2 ? Op : Oh;
            *(uint4*)&O[(size_t)gr * 128 + colq * 8] = v;
        }
    }
}

// ---------------- scan hierarchy (R8) ----------------

__global__ __launch_bounds__(256) void scan_block_sum(const int* __restrict__ cnt, int* __restrict__ bsum,
                                                      float* __restrict__ dis, int N) {
    __shared__ int s[256];
    int i = blockIdx.x * 256 + threadIdx.x;
    int c = (i < N) ? cnt[i] : -1;
    int v = (i < N) ? c + 1 : 0;
    if (i < N) dis[i] = rsqrtf((float)c + 2.0f);
    s[threadIdx.x] = v;
    __syncthreads();
    for (int o = 128; o > 0; o >>= 1) {
        if (threadIdx.x < o) s[threadIdx.x] += s[threadIdx.x + o];
        __syncthreads();
    }
    if (threadIdx.x == 0) bsum[blockIdx.x] = s[0];
}

__global__ void scan_tops(const int* __restrict__ bsum, int* __restrict__ boff, int* __restrict__ rowptrN, int nb) {
    __shared__ int s[256];
    int t = threadIdx.x;
    int v = (t < nb) ? bsum[t] : 0;
    s[t] = v;
    __syncthreads();
    for (int o = 1; o < 256; o <<= 1) {
        int u = (t >= o) ? s[t - o] : 0;
        __syncthreads();
        s[t] += u;
        __syncthreads();
    }
    if (t < nb) boff[t] = s[t] - v;
    if (t == 255) *rowptrN = s[255];
}

__global__ __launch_bounds__(256) void scan_final(const int* __restrict__ cnt, const int* __restrict__ boff,
                                                  const float* __restrict__ dis,
                                                  int* __restrict__ rowptr, int* __restrict__ cursor,
                                                  int2* __restrict__ recs, int N) {
    __shared__ int s[256];
    int t = threadIdx.x;
    int i = blockIdx.x * 256 + t;
    int v = (i < N) ? cnt[i] + 1 : 0;
    s[t] = v;
    __syncthreads();
    for (int o = 1; o < 256; o <<= 1) {
        int u = (t >= o) ? s[t - o] : 0;
        __syncthreads();
        s[t] += u;
        __syncthreads();
    }
    if (i < N) {
        int e = boff[blockIdx.x] + s[t] - v;
        rowptr[i] = e;
        cursor[i] = e + 1;                    // slot e holds the self record
        float d = dis[i];
        int2 r; r.x = i; r.y = f2i(2.0f * d * d);
        recs[e] = r;
    }
}

// XCD-partitioned fill; writes (src, dis[src]*dis[dst]) records
__global__ __launch_bounds__(256) void fill_xcd(const int* __restrict__ ei, int E, int nper,
                                                const float* __restrict__ dis,
                                                int* __restrict__ cursor, int2* __restrict__ recs) {
    int xcd = blockIdx.x & 7;
    int nchunk = gridDim.x >> 3;
    int chunk = blockIdx.x >> 3;
    int csz = (E + nchunk - 1) / nchunk;
    int beg = chunk * csz;
    int end = min(E, beg + csz);
    for (int e = beg + (int)threadIdx.x; e < end; e += 256) {
        int c = ei[E + e];
        if (c / nper == xcd) {
            int r = ei[e];
            int slot = atomicAdd(&cursor[c], 1);
            int2 rec; rec.x = r; rec.y = f2i(dis[r] * dis[c]);
            recs[slot] = rec;
        }
    }
}

// ---------------- aggregation: wave per node, half-wave split, 4 records in flight per half ----------------

__global__ __launch_bounds__(256) void aggregate_rec(const ushortT* __restrict__ h,
                                                     const int* __restrict__ rowptr,
                                                     const int2* __restrict__ recs,
                                                     ushortT* __restrict__ aggb, int N) {
    int n = blockIdx.x * 4 + (threadIdx.x >> 6);
    if (n >= N) return;
    int lane = threadIdx.x & 63;
    int half = lane >> 5, cl = lane & 31;
    int beg = rowptr[n], end = rowptr[n + 1];
    const uint2* h2 = (const uint2*)h;           // 8B units; row stride 32
    float a0 = 0.f, a1 = 0.f, a2 = 0.f, a3 = 0.f;
    float b0 = 0.f, b1 = 0.f, b2 = 0.f, b3 = 0.f;
    float c0 = 0.f, c1 = 0.f, c2 = 0.f, c3 = 0.f;
    float d0 = 0.f, d1 = 0.f, d2 = 0.f, d3 = 0.f;
    int idx = beg + half;
    // main: 4 records per half per iteration (8 rows in flight per wave)
    for (; idx + 6 < end; idx += 8) {
        int2 r0 = recs[idx];
        int2 r1 = recs[idx + 2];
        int2 r2 = recs[idx + 4];
        int2 r3 = recs[idx + 6];
        uint2 v0 = h2[(size_t)r0.x * 32 + cl];
        uint2 v1 = h2[(size_t)r1.x * 32 + cl];
        uint2 v2 = h2[(size_t)r2.x * 32 + cl];
        uint2 v3 = h2[(size_t)r3.x * 32 + cl];
        float n0 = i2f(r0.y), n1 = i2f(r1.y), n2 = i2f(r2.y), n3 = i2f(r3.y);
        a0 = fmaf(n0, bflo(v0.x), a0); a1 = fmaf(n0, bfhi(v0.x), a1);
        a2 = fmaf(n0, bflo(v0.y), a2); a3 = fmaf(n0, bfhi(v0.y), a3);
        b0 = fmaf(n1, bflo(v1.x), b0); b1 = fmaf(n1, bfhi(v1.x), b1);
        b2 = fmaf(n1, bflo(v1.y), b2); b3 = fmaf(n1, bfhi(v1.y), b3);
        c0 = fmaf(n2, bflo(v2.x), c0); c1 = fmaf(n2, bfhi(v2.x), c1);
        c2 = fmaf(n2, bflo(v2.y), c2); c3 = fmaf(n2, bfhi(v2.y), c3);
        d0 = fmaf(n3, bflo(v3.x), d0); d1 = fmaf(n3, bfhi(v3.x), d1);
        d2 = fmaf(n3, bflo(v3.y), d2); d3 = fmaf(n3, bfhi(v3.y), d3);
    }
    // tail: up to 3 leftover records per half
    for (; idx < end; idx += 2) {
        int2 r0 = recs[idx];
        uint2 v0 = h2[(size_t)r0.x * 32 + cl];
        float n0 = i2f(r0.y);
        a0 = fmaf(n0, bflo(v0.x), a0); a1 = fmaf(n0, bfhi(v0.x), a1);
        a2 = fmaf(n0, bflo(v0.y), a2); a3 = fmaf(n0, bfhi(v0.y), a3);
    }
    a0 = (a0 + b0) + (c0 + d0);
    a1 = (a1 + b1) + (c1 + d1);
    a2 = (a2 + b2) + (c2 + d2);
    a3 = (a3 + b3) + (c3 + d3);
    a0 += __shfl_xor(a0, 32);
    a1 += __shfl_xor(a1, 32);
    a2 += __shfl_xor(a2, 32);
    a3 += __shfl_xor(a3, 32);
    if (half == 0) {
        uint2 o;
        o.x = pk2(a0, a1);
        o.y = pk2(a2, a3);
        ((uint2*)aggb)[(size_t)n * 32 + cl] = o;
    }
}

// ---------------- BN stats from bf16 (raw sums) ----------------

__global__ __launch_bounds__(256) void stats_bf(const unsigned* __restrict__ v, int totalU,
                                                float* __restrict__ sums) {
    int tid = blockIdx.x * 256 + threadIdx.x;
    int stride = gridDim.x * 256;
    float sx = 0.f, sy = 0.f, qx = 0.f, qy = 0.f;
    for (int i = tid; i < totalU; i += stride) {
        unsigned u = v[i];
        float a = bflo(u), b = bfhi(u);
        sx += a; sy += b;
        qx = fmaf(a, a, qx); qy = fmaf(b, b, qy);
    }
    __shared__ float l0[256], l1[256], l2[256], l3[256];
    int t = threadIdx.x;
    l0[t] = sx; l1[t] = sy; l2[t] = qx; l3[t] = qy;
    __syncthreads();
    if (t < 64) {
        sx = (l0[t] + l0[t + 64]) + (l0[t + 128] + l0[t + 192]);
        sy = (l1[t] + l1[t + 64]) + (l1[t + 128] + l1[t + 192]);
        qx = (l2[t] + l2[t + 64]) + (l2[t + 128] + l2[t + 192]);
        qy = (l3[t] + l3[t + 64]) + (l3[t + 128] + l3[t + 192]);
        atomicAdd(&sums[2 * t], sx);
        atomicAdd(&sums[2 * t + 1], sy);
        atomicAdd(&sums[128 + 2 * t], qx);
        atomicAdd(&sums[128 + 2 * t + 1], qy);
    }
}

// ---------------- GEMM1 fused: x1 = relu(bn0(agg)) + proj (written out), h = x1 @ W1, LDS epilogue ----------------

__global__ __launch_bounds__(512) void mgemm1_fused(const uint4* __restrict__ aggb,
                                                    const uint4* __restrict__ projb,
                                                    const float* __restrict__ stats,
                                                    const float* __restrict__ g,
                                                    const float* __restrict__ be,
                                                    const ushortT* __restrict__ Wt1,
                                                    ushortT* __restrict__ O,
                                                    uint4* __restrict__ x1b,
                                                    int N) {
    __shared__ __align__(16) ushortT S[17408];
    __shared__ float sc[128], sh[128];
    int tid = threadIdx.x;
    int brow = blockIdx.x * 128;

    if (tid < 128) {
        float mean = stats[tid] / (float)N;
        float var = stats[128 + tid] / (float)N - mean * mean;
        float inv = rsqrtf(var + EPS);
        float s = g[tid] * inv;
        sc[tid] = s;
        sh[tid] = be[tid] - mean * s;
    }
    __syncthreads();

#pragma unroll
    for (int i = 0; i < 4; ++i) {
        int idx = i * 512 + tid;
        int row = idx >> 4, q = idx & 15;
        int gr = brow + row;
        uint4 a = make_uint4(0u, 0u, 0u, 0u), p = a;
        if (gr < N) {
            size_t gidx = (size_t)gr * 16 + q;
            a = aggb[gidx];
            p = projb[gidx];
        }
        int ch = q * 8;
        float v0 = fmaxf(fmaf(bflo(a.x), sc[ch + 0], sh[ch + 0]), 0.f) + bflo(p.x);
        float v1 = fmaxf(fmaf(bfhi(a.x), sc[ch + 1], sh[ch + 1]), 0.f) + bfhi(p.x);
        float v2 = fmaxf(fmaf(bflo(a.y), sc[ch + 2], sh[ch + 2]), 0.f) + bflo(p.y);
        float v3 = fmaxf(fmaf(bfhi(a.y), sc[ch + 3], sh[ch + 3]), 0.f) + bfhi(p.y);
        float v4 = fmaxf(fmaf(bflo(a.z), sc[ch + 4], sh[ch + 4]), 0.f) + bflo(p.z);
        float v5 = fmaxf(fmaf(bfhi(a.z), sc[ch + 5], sh[ch + 5]), 0.f) + bfhi(p.z);
        float v6 = fmaxf(fmaf(bflo(a.w), sc[ch + 6], sh[ch + 6]), 0.f) + bflo(p.w);
        float v7 = fmaxf(fmaf(bfhi(a.w), sc[ch + 7], sh[ch + 7]), 0.f) + bfhi(p.w);
        uint4 pv;
        pv.x = pk2(v0, v1);
        pv.y = pk2(v2, v3);
        pv.z = pk2(v4, v5);
        pv.w = pk2(v6, v7);
        *(uint4*)&S[row * 136 + q * 8] = pv;
        if (gr < N) x1b[(size_t)gr * 16 + q] = pv;
    }
    __syncthreads();

    int w = tid >> 6, lane = tid & 63;
    int lm = lane & 15, lk = lane >> 4;
    int rh = (w >> 2) * 64;
    int colbase = (w & 3) * 32;

    bf16x8 breg[2][4];
#pragma unroll
    for (int nt = 0; nt < 2; ++nt)
#pragma unroll
        for (int ks = 0; ks < 4; ++ks)
            breg[nt][ks] = *(const bf16x8*)&Wt1[(size_t)(colbase + nt * 16 + lm) * H + ks * 32 + lk * 8];

    f32x4 acc[4][2];
#pragma unroll
    for (int mt = 0; mt < 4; ++mt)
#pragma unroll
        for (int nt = 0; nt < 2; ++nt) acc[mt][nt] = (f32x4)0.f;

#pragma unroll
    for (int ks = 0; ks < 4; ++ks) {
        bf16x8 af[4];
#pragma unroll
        for (int mt = 0; mt < 4; ++mt)
            af[mt] = *(const bf16x8*)&S[(rh + mt * 16 + lm) * 136 + ks * 32 + lk * 8];
#pragma unroll
        for (int nt = 0; nt < 2; ++nt)
#pragma unroll
            for (int mt = 0; mt < 4; ++mt)
                acc[mt][nt] = __builtin_amdgcn_mfma_f32_16x16x32_bf16(af[mt], breg[nt][ks], acc[mt][nt], 0, 0, 0);
    }

    __syncthreads();
#pragma unroll
    for (int mt = 0; mt < 4; ++mt)
#pragma unroll
        for (int nt = 0; nt < 2; ++nt) {
            int col = colbase + nt * 16 + lm;
#pragma unroll
            for (int j = 0; j < 4; ++j) {
                int row = rh + mt * 16 + lk * 4 + j;
                S[row * 136 + col] = f2bf(acc[mt][nt][j]);
            }
        }
    __syncthreads();
#pragma unroll
    for (int i = 0; i < 4; ++i) {
        int idx = i * 512 + tid;
        int row = idx >> 4, colq = idx & 15;
        int gr = brow + row;
        if (gr < N) {
            uint4 v = *(const uint4*)&S[row * 136 + colq * 8];
            *(uint4*)&O[(size_t)gr * 128 + colq * 8] = v;
        }
    }
}

// ---------------- head: out = (relu(bn1(agg)) + x1) @ hW + hb, x2 inline ----------------

__global__ __launch_bounds__(256) void head_fused(const uint4* __restrict__ aggb,
                                                  const uint4* __restrict__ x1b,
                                                  const float* __restrict__ stats,
                                                  const float* __restrict__ g,
                                                  const float* __restrict__ be,
                                                  const ushortT* __restrict__ WtH,
                                                  const float* __restrict__ hb,
                                                  float* __restrict__ out, int N) {
    __shared__ __align__(16) ushortT As[64][136];
    __shared__ __align__(16) ushortT Bs[48][136];
    __shared__ float sc[128], sh[128];

    int tid = threadIdx.x;
    int brow = blockIdx.x * 64;
    int w = tid >> 6, lane = tid & 63;
    int lm = lane & 15, lk = lane >> 4;

    if (tid < 128) {
        float mean = stats[tid] / (float)N;
        float var = stats[128 + tid] / (float)N - mean * mean;
        float inv = rsqrtf(var + EPS);
        float s = g[tid] * inv;
        sc[tid] = s;
        sh[tid] = be[tid] - mean * s;
    }
    if (tid < 192) {
        int row = tid >> 2, q = tid & 3;
        const uint4* src = (const uint4*)&WtH[(size_t)row * H + q * 32];
        uint4 a = src[0], b = src[1], c = src[2], d = src[3];
        uint4* dst = (uint4*)&Bs[row][q * 32];
        dst[0] = a; dst[1] = b; dst[2] = c; dst[3] = d;
    }
    __syncthreads();
#pragma unroll
    for (int k = 0; k < 4; ++k) {
        int idx = k * 256 + tid;
        int row = idx >> 4, colq = idx & 15;
        int gr = brow + row;
        uint4 a = make_uint4(0u, 0u, 0u, 0u), x = a;
        if (gr < N) {
            size_t gidx = (size_t)brow * 16 + idx;
            a = aggb[gidx];
            x = x1b[gidx];
        }
        int ch = colq * 8;
        float v0 = fmaxf(fmaf(bflo(a.x), sc[ch + 0], sh[ch + 0]), 0.f) + bflo(x.x);
        float v1 = fmaxf(fmaf(bfhi(a.x), sc[ch + 1], sh[ch + 1]), 0.f) + bfhi(x.x);
        float v2 = fmaxf(fmaf(bflo(a.y), sc[ch + 2], sh[ch + 2]), 0.f) + bflo(x.y);
        float v3 = fmaxf(fmaf(bfhi(a.y), sc[ch + 3], sh[ch + 3]), 0.f) + bfhi(x.y);
        float v4 = fmaxf(fmaf(bflo(a.z), sc[ch + 4], sh[ch + 4]), 0.f) + bflo(x.z);
        float v5 = fmaxf(fmaf(bfhi(a.z), sc[ch + 5], sh[ch + 5]), 0.f) + bfhi(x.z);
        float v6 = fmaxf(fmaf(bflo(a.w), sc[ch + 6], sh[ch + 6]), 0.f) + bflo(x.w);
        float v7 = fmaxf(fmaf(bfhi(a.w), sc[ch + 7], sh[ch + 7]), 0.f) + bfhi(x.w);
        uint4 pv;
        pv.x = pk2(v0, v1);
        pv.y = pk2(v2, v3);
        pv.z = pk2(v4, v5);
        pv.w = pk2(v6, v7);
        *(uint4*)&As[row][colq * 8] = pv;
    }
    __syncthreads();

    f32x4 acc[3];
#pragma unroll
    for (int nt = 0; nt < 3; ++nt) acc[nt] = (f32x4)0.f;
#pragma unroll
    for (int ks = 0; ks < 4; ++ks) {
        bf16x8 a = *(const bf16x8*)&As[w * 16 + lm][ks * 32 + lk * 8];
#pragma unroll
        for (int nt = 0; nt < 3; ++nt) {
            bf16x8 b = *(const bf16x8*)&Bs[nt * 16 + lm][ks * 32 + lk * 8];
            acc[nt] = __builtin_amdgcn_mfma_f32_16x16x32_bf16(a, b, acc[nt], 0, 0, 0);
        }
    }
#pragma unroll
    for (int nt = 0; nt < 3; ++nt) {
        int col = nt * 16 + lm;
        if (col < OUT_DIM) {
            float bbv = hb[col];
#pragma unroll
            for (int j = 0; j < 4; ++j) {
                int r = brow + w * 16 + lk * 4 + j;
                if (r < N) out[(size_t)r * OUT_DIM + col] = acc[nt][j] + bbv;
            }
        }
    }
}

// ---------------- launch ----------------

extern "C" void kernel_launch(void* const* d_in, const int* in_sizes, int n_in,
                              void* d_out, int out_size, void* d_ws, size_t ws_size,
                              hipStream_t stream) {
    const float* x   = (const float*)d_in[0];
    const int*   ei  = (const int*)d_in[1];
    const float* W0  = (const float*)d_in[2];
    // d_in[3] = b0: cancels in BatchNorm
    const float* g0  = (const float*)d_in[4];
    const float* be0 = (const float*)d_in[5];
    const float* pW  = (const float*)d_in[6];
    const float* pb  = (const float*)d_in[7];
    const float* W1  = (const float*)d_in[8];
    // d_in[9] = b1: cancels in BatchNorm
    const float* g1  = (const float*)d_in[10];
    const float* be1 = (const float*)d_in[11];
    const float* hW  = (const float*)d_in[12];
    const float* hb  = (const float*)d_in[13];
    float* out = (float*)d_out;

    int N = in_sizes[0] / IN_DIM;
    int E = in_sizes[1] / 2;
    size_t NH = (size_t)N * H;

    // workspace layout (all bf16 intermediates)
    ushortT* hb16   = (ushortT*)d_ws;            // [N,128] conv input h
    ushortT* aggb   = hb16 + NH;                 // [N,128] aggregated
    ushortT* projb  = aggb + NH;                 // [N,128] proj (block0)
    ushortT* x1b    = projb + NH;                // [N,128] x1
    float*   dis    = (float*)(x1b + NH);        // [N]
    int*     cnt    = (int*)(dis + N);           // [N]
    int*     rowptr = cnt + N;                   // [N+1]
    int*     cursor = rowptr + (N + 1);          // [N]
    int2*    recs   = (int2*)(cursor + N);       // [E+N] (8B-aligned)
    float*   stats  = (float*)(recs + (E + N));  // [512]: conv0 then conv1
    ushortT* Wt0    = (ushortT*)(stats + 512);   // [128*256]
    ushortT* WtP    = Wt0 + 128 * 256;           // [128*256]
    ushortT* Wt1    = WtP + 128 * 256;           // [128*128]
    ushortT* WtH    = Wt1 + 128 * 128;           // [48*128]
    int*     bsum   = (int*)(WtH + 48 * 128);    // [256]
    int*     boff   = bsum + 256;                // [256]
    float*   stats0 = stats;
    float*   stats1 = stats + 256;

    int nb = (N + 255) / 256;
    int g64 = (N + 63) / 64;
    int g128 = (N + 127) / 128;
    int gAgg = (N + 3) / 4;
    int nper = (N + 7) / 8;
    const int CNT_BLOCKS = 1024;                 // count role blocks (multiple of 8)

    // prep (weights + zero cnt/stats)
    prep_weights<<<196, 256, 0, stream>>>(W0, pW, W1, hW, Wt0, WtP, Wt1, WtH, cnt, stats, N);

    // GEMM0 (dual) + degree count in one dispatch
    gemm0_count<<<g64 + CNT_BLOCKS, 512, 0, stream>>>(x, Wt0, WtP, pb, hb16, projb,
                                                      ei, cnt, N, E, nper, g64);

    // CSR offsets + records
    scan_block_sum<<<nb, 256, 0, stream>>>(cnt, bsum, dis, N);
    scan_tops<<<1, 256, 0, stream>>>(bsum, boff, &rowptr[N], nb);
    scan_final<<<nb, 256, 0, stream>>>(cnt, boff, dis, rowptr, cursor, recs, N);
    fill_xcd<<<2048, 256, 0, stream>>>(ei, E, nper, dis, cursor, recs);

    // block 0
    aggregate_rec<<<gAgg, 256, 0, stream>>>(hb16, rowptr, recs, aggb, N);
    stats_bf<<<256, 256, 0, stream>>>((const unsigned*)aggb, (int)(NH / 2), stats0);

    // block 1 (x1 = relu(bn0(agg)) + proj fused into GEMM1's staging; x1 also written for head)
    mgemm1_fused<<<g128, 512, 0, stream>>>((const uint4*)aggb, (const uint4*)projb, stats0, g0, be0,
                                           Wt1, hb16, (uint4*)x1b, N);
    aggregate_rec<<<gAgg, 256, 0, stream>>>(hb16, rowptr, recs, aggb, N);
    stats_bf<<<256, 256, 0, stream>>>((const unsigned*)aggb, (int)(NH / 2), stats1);

    // head (x2 computed inline)
    head_fused<<<g64, 256, 0, stream>>>((const uint4*)aggb, (const uint4*)x1b, stats1, g1, be1,
                                        WtH, hb, out, N);
}

// Round 12
// 238.633 us; speedup vs baseline: 31.4633x; 1.0253x over previous
//
#include <hip/hip_runtime.h>

#define H 128
#define IN_DIM 256
#define OUT_DIM 40
#define EPS 1e-5f

typedef unsigned short ushortT;
typedef __attribute__((ext_vector_type(8))) short bf16x8;
typedef __attribute__((ext_vector_type(4))) float f32x4;

static __device__ __forceinline__ ushortT f2bf(float f) {
    union { float f; unsigned u; } v; v.f = f;
    unsigned r = v.u + 0x7FFF + ((v.u >> 16) & 1);   // RNE
    return (ushortT)(r >> 16);
}
static __device__ __forceinline__ unsigned pk2(float a, float b) {
    return (unsigned)f2bf(a) | ((unsigned)f2bf(b) << 16);
}
static __device__ __forceinline__ float bflo(unsigned v) {
    union { unsigned u; float f; } t; t.u = v << 16; return t.f;
}
static __device__ __forceinline__ float bfhi(unsigned v) {
    union { unsigned u; float f; } t; t.u = v & 0xFFFF0000u; return t.f;
}
static __device__ __forceinline__ float i2f(int v) {
    union { int i; float f; } t; t.i = v; return t.f;
}
static __device__ __forceinline__ int f2i(float v) {
    union { float f; int i; } t; t.f = v; return t.i;
}

// ---------------- weight prep: transpose + bf16 (also zeroes cnt + stats) ----------------

__global__ __launch_bounds__(256) void prep_weights(const float* __restrict__ W0, const float* __restrict__ pW,
                                                    const float* __restrict__ W1, const float* __restrict__ hW,
                                                    ushortT* __restrict__ Wt0, ushortT* __restrict__ WtP,
                                                    ushortT* __restrict__ Wt1, ushortT* __restrict__ WtH,
                                                    int* __restrict__ cnt, float* __restrict__ stats, int N) {
    int i = blockIdx.x * 256 + threadIdx.x;
    if (i < 32768) { int n = i >> 8, k = i & 255; Wt0[i] = f2bf(W0[k * 128 + n]); WtP[i] = f2bf(pW[k * 128 + n]); }
    if (i < 16384) { int n = i >> 7, k = i & 127; Wt1[i] = f2bf(W1[k * 128 + n]); }
    if (i < 6144)  { int n = i >> 7, k = i & 127; WtH[i] = (n < OUT_DIM) ? f2bf(hW[k * OUT_DIM + n]) : (ushortT)0; }
    if (i < N) cnt[i] = 0;
    if (i < 512) stats[i] = 0.f;
}

// ---------------- GEMM0 (persistent 2-tile, cross-tile prefetch, LDS epilogue) + degree count ----------------
// blocks [0, gemmBlocks): persistent dual GEMM; each handles tiles {bid, bid+G, ...}.
// blocks [gemmBlocks, ...): XCD-partitioned degree count (independent of GEMM).

static __device__ __forceinline__ void g0_loads(const float* __restrict__ X, int brow, int kc,
                                                int tid, int N, float4 pf[4]) {
#pragma unroll
    for (int i = 0; i < 4; ++i) {
        int idx = i * 512 + tid;
        int row = idx >> 5, c4 = idx & 31;
        int gr = brow + row;
        pf[i] = make_float4(0.f, 0.f, 0.f, 0.f);
        if (gr < N) pf[i] = *(const float4*)&X[(size_t)gr * IN_DIM + kc * 128 + c4 * 4];
    }
}
static __device__ __forceinline__ void g0_write(ushortT* __restrict__ Sbuf, int tid, const float4 pf[4]) {
#pragma unroll
    for (int i = 0; i < 4; ++i) {
        int idx = i * 512 + tid;
        int row = idx >> 5, c4 = idx & 31;
        uint2 p;
        p.x = pk2(pf[i].x, pf[i].y);
        p.y = pk2(pf[i].z, pf[i].w);
        *(uint2*)&Sbuf[row * 136 + c4 * 4] = p;
    }
}

__global__ __launch_bounds__(512) void gemm0_count(const float* __restrict__ X,
                                                   const ushortT* __restrict__ Wt0,
                                                   const ushortT* __restrict__ WtP,
                                                   const float* __restrict__ pb,
                                                   ushortT* __restrict__ Oh,
                                                   ushortT* __restrict__ Op,
                                                   const int* __restrict__ ei,
                                                   int* __restrict__ cnt,
                                                   int N, int E, int nper,
                                                   int gemmBlocks, int ntiles) {
    __shared__ __align__(16) ushortT S2[2][64 * 136];
    ushortT* Sf = &S2[0][0];
    int tid = threadIdx.x;

    if (blockIdx.x >= gemmBlocks) {
        // ---- count role ----
        int cbid = blockIdx.x - gemmBlocks;
        int xcd = cbid & 7;
        int nchunk = (gridDim.x - gemmBlocks) >> 3;
        int chunk = cbid >> 3;
        int csz = (E + nchunk - 1) / nchunk;
        int beg = chunk * csz;
        int end = min(E, beg + csz);
        for (int e = beg + tid; e < end; e += 512) {
            int c = ei[E + e];
            if (c / nper == xcd) atomicAdd(&cnt[c], 1);
        }
        return;
    }

    // ---- persistent GEMM role ----
    int w = tid >> 6, lane = tid & 63;
    int lm = lane & 15, lk = lane >> 4;
    int mat = w >> 2;
    int colbase = (w & 3) * 32;
    const ushortT* Wt = mat ? WtP : Wt0;

    // B in regs ONCE per block (amortized over all tiles)
    bf16x8 breg[2][8];
#pragma unroll
    for (int nt = 0; nt < 2; ++nt)
#pragma unroll
        for (int kk = 0; kk < 8; ++kk)
            breg[nt][kk] = *(const bf16x8*)&Wt[(size_t)(colbase + nt * 16 + lm) * IN_DIM + kk * 32 + lk * 8];
    float bb[2];
    bb[0] = mat ? pb[colbase + lm] : 0.f;
    bb[1] = mat ? pb[colbase + 16 + lm] : 0.f;
    ushortT* O = mat ? Op : Oh;

    int G = gemmBlocks;
    int t = blockIdx.x;
    float4 pf[4];
    if (t < ntiles) g0_loads(X, t * 64, 0, tid, N, pf);    // prologue: chunk0 of first tile

    for (; t < ntiles; t += G) {
        int brow = t * 64;
        g0_write(Sf, tid, pf);                  // chunk0 -> S2[0]
        __syncthreads();                        // buf0 staged
        g0_loads(X, brow, 1, tid, N, pf);       // issue chunk1 early (hides under chunk0 MFMA)

        f32x4 acc[4][2];
#pragma unroll
        for (int mt = 0; mt < 4; ++mt)
#pragma unroll
            for (int nt = 0; nt < 2; ++nt) acc[mt][nt] = (f32x4)0.f;

        // MFMA chunk 0
#pragma unroll
        for (int kk = 0; kk < 4; ++kk) {
            bf16x8 af[4];
#pragma unroll
            for (int mt = 0; mt < 4; ++mt)
                af[mt] = *(const bf16x8*)&Sf[(mt * 16 + lm) * 136 + kk * 32 + lk * 8];
#pragma unroll
            for (int nt = 0; nt < 2; ++nt)
#pragma unroll
                for (int mt = 0; mt < 4; ++mt)
                    acc[mt][nt] = __builtin_amdgcn_mfma_f32_16x16x32_bf16(af[mt], breg[nt][kk], acc[mt][nt], 0, 0, 0);
        }
        g0_write(Sf + 8704, tid, pf);           // chunk1 -> S2[1]
        __syncthreads();                        // buf1 staged
        int tn = t + G;
        if (tn < ntiles) g0_loads(X, tn * 64, 0, tid, N, pf);   // cross-tile prefetch: next chunk0

        // MFMA chunk 1
#pragma unroll
        for (int kk = 0; kk < 4; ++kk) {
            bf16x8 af[4];
#pragma unroll
            for (int mt = 0; mt < 4; ++mt)
                af[mt] = *(const bf16x8*)&Sf[8704 + (mt * 16 + lm) * 136 + kk * 32 + lk * 8];
#pragma unroll
            for (int nt = 0; nt < 2; ++nt)
#pragma unroll
                for (int mt = 0; mt < 4; ++mt)
                    acc[mt][nt] = __builtin_amdgcn_mfma_f32_16x16x32_bf16(af[mt], breg[nt][4 + kk], acc[mt][nt], 0, 0, 0);
        }
        __syncthreads();                        // all LDS A-reads done; reuse as C
        // C staging: mat m -> half m, row stride 136
#pragma unroll
        for (int mt = 0; mt < 4; ++mt)
#pragma unroll
            for (int nt = 0; nt < 2; ++nt) {
                int col = colbase + nt * 16 + lm;
#pragma unroll
                for (int j = 0; j < 4; ++j) {
                    int row = mt * 16 + lk * 4 + j;
                    Sf[mat * 8704 + row * 136 + col] = f2bf(acc[mt][nt][j] + bb[nt]);
                }
            }
        __syncthreads();
        // coalesced stores: 2048 uint4 (2 mats x 64 rows x 16 uint4), 4/thread
#pragma unroll
        for (int i = 0; i < 4; ++i) {
            int idx = i * 512 + tid;
            int m2 = idx >> 10;
            int rem = idx & 1023;
            int row = rem >> 4, colq = rem & 15;
            int gr = brow + row;
            if (gr < N) {
                uint4 v = *(const uint4*)&Sf[m2 * 8704 + row * 136 + colq * 8];
                ushortT* Od = m2 ? Op : Oh;
                *(uint4*)&Od[(size_t)gr * 128 + colq * 8] = v;
            }
        }
        __syncthreads();                        // LDS store-reads done before next tile overwrites
    }
}

// ---------------- scan hierarchy ----------------

__global__ __launch_bounds__(256) void scan_block_sum(const int* __restrict__ cnt, int* __restrict__ bsum,
                                                      float* __restrict__ dis, int N) {
    __shared__ int s[256];
    int i = blockIdx.x * 256 + threadIdx.x;
    int c = (i < N) ? cnt[i] : -1;
    int v = (i < N) ? c + 1 : 0;
    if (i < N) dis[i] = rsqrtf((float)c + 2.0f);
    s[threadIdx.x] = v;
    __syncthreads();
    for (int o = 128; o > 0; o >>= 1) {
        if (threadIdx.x < o) s[threadIdx.x] += s[threadIdx.x + o];
        __syncthreads();
    }
    if (threadIdx.x == 0) bsum[blockIdx.x] = s[0];
}

__global__ void scan_tops(const int* __restrict__ bsum, int* __restrict__ boff, int* __restrict__ rowptrN, int nb) {
    __shared__ int s[256];
    int t = threadIdx.x;
    int v = (t < nb) ? bsum[t] : 0;
    s[t] = v;
    __syncthreads();
    for (int o = 1; o < 256; o <<= 1) {
        int u = (t >= o) ? s[t - o] : 0;
        __syncthreads();
        s[t] += u;
        __syncthreads();
    }
    if (t < nb) boff[t] = s[t] - v;
    if (t == 255) *rowptrN = s[255];
}

__global__ __launch_bounds__(256) void scan_final(const int* __restrict__ cnt, const int* __restrict__ boff,
                                                  const float* __restrict__ dis,
                                                  int* __restrict__ rowptr, int* __restrict__ cursor,
                                                  int2* __restrict__ recs, int N) {
    __shared__ int s[256];
    int t = threadIdx.x;
    int i = blockIdx.x * 256 + t;
    int v = (i < N) ? cnt[i] + 1 : 0;
    s[t] = v;
    __syncthreads();
    for (int o = 1; o < 256; o <<= 1) {
        int u = (t >= o) ? s[t - o] : 0;
        __syncthreads();
        s[t] += u;
        __syncthreads();
    }
    if (i < N) {
        int e = boff[blockIdx.x] + s[t] - v;
        rowptr[i] = e;
        cursor[i] = e + 1;                    // slot e holds the self record
        float d = dis[i];
        int2 r; r.x = i; r.y = f2i(2.0f * d * d);
        recs[e] = r;
    }
}

// XCD-partitioned fill; writes (src, dis[src]*dis[dst]) records
__global__ __launch_bounds__(256) void fill_xcd(const int* __restrict__ ei, int E, int nper,
                                                const float* __restrict__ dis,
                                                int* __restrict__ cursor, int2* __restrict__ recs) {
    int xcd = blockIdx.x & 7;
    int nchunk = gridDim.x >> 3;
    int chunk = blockIdx.x >> 3;
    int csz = (E + nchunk - 1) / nchunk;
    int beg = chunk * csz;
    int end = min(E, beg + csz);
    for (int e = beg + (int)threadIdx.x; e < end; e += 256) {
        int c = ei[E + e];
        if (c / nper == xcd) {
            int r = ei[e];
            int slot = atomicAdd(&cursor[c], 1);
            int2 rec; rec.x = r; rec.y = f2i(dis[r] * dis[c]);
            recs[slot] = rec;
        }
    }
}

// ---------------- aggregation: wave per node, half-wave split, 4 records in flight per half ----------------

__global__ __launch_bounds__(256) void aggregate_rec(const ushortT* __restrict__ h,
                                                     const int* __restrict__ rowptr,
                                                     const int2* __restrict__ recs,
                                                     ushortT* __restrict__ aggb, int N) {
    int n = blockIdx.x * 4 + (threadIdx.x >> 6);
    if (n >= N) return;
    int lane = threadIdx.x & 63;
    int half = lane >> 5, cl = lane & 31;
    int beg = rowptr[n], end = rowptr[n + 1];
    const uint2* h2 = (const uint2*)h;           // 8B units; row stride 32
    float a0 = 0.f, a1 = 0.f, a2 = 0.f, a3 = 0.f;
    float b0 = 0.f, b1 = 0.f, b2 = 0.f, b3 = 0.f;
    float c0 = 0.f, c1 = 0.f, c2 = 0.f, c3 = 0.f;
    float d0 = 0.f, d1 = 0.f, d2 = 0.f, d3 = 0.f;
    int idx = beg + half;
    // main: 4 records per half per iteration (8 rows in flight per wave)
    for (; idx + 6 < end; idx += 8) {
        int2 r0 = recs[idx];
        int2 r1 = recs[idx + 2];
        int2 r2 = recs[idx + 4];
        int2 r3 = recs[idx + 6];
        uint2 v0 = h2[(size_t)r0.x * 32 + cl];
        uint2 v1 = h2[(size_t)r1.x * 32 + cl];
        uint2 v2 = h2[(size_t)r2.x * 32 + cl];
        uint2 v3 = h2[(size_t)r3.x * 32 + cl];
        float n0 = i2f(r0.y), n1 = i2f(r1.y), n2 = i2f(r2.y), n3 = i2f(r3.y);
        a0 = fmaf(n0, bflo(v0.x), a0); a1 = fmaf(n0, bfhi(v0.x), a1);
        a2 = fmaf(n0, bflo(v0.y), a2); a3 = fmaf(n0, bfhi(v0.y), a3);
        b0 = fmaf(n1, bflo(v1.x), b0); b1 = fmaf(n1, bfhi(v1.x), b1);
        b2 = fmaf(n1, bflo(v1.y), b2); b3 = fmaf(n1, bfhi(v1.y), b3);
        c0 = fmaf(n2, bflo(v2.x), c0); c1 = fmaf(n2, bfhi(v2.x), c1);
        c2 = fmaf(n2, bflo(v2.y), c2); c3 = fmaf(n2, bfhi(v2.y), c3);
        d0 = fmaf(n3, bflo(v3.x), d0); d1 = fmaf(n3, bfhi(v3.x), d1);
        d2 = fmaf(n3, bflo(v3.y), d2); d3 = fmaf(n3, bfhi(v3.y), d3);
    }
    // tail: up to 3 leftover records per half
    for (; idx < end; idx += 2) {
        int2 r0 = recs[idx];
        uint2 v0 = h2[(size_t)r0.x * 32 + cl];
        float n0 = i2f(r0.y);
        a0 = fmaf(n0, bflo(v0.x), a0); a1 = fmaf(n0, bfhi(v0.x), a1);
        a2 = fmaf(n0, bflo(v0.y), a2); a3 = fmaf(n0, bfhi(v0.y), a3);
    }
    a0 = (a0 + b0) + (c0 + d0);
    a1 = (a1 + b1) + (c1 + d1);
    a2 = (a2 + b2) + (c2 + d2);
    a3 = (a3 + b3) + (c3 + d3);
    a0 += __shfl_xor(a0, 32);
    a1 += __shfl_xor(a1, 32);
    a2 += __shfl_xor(a2, 32);
    a3 += __shfl_xor(a3, 32);
    if (half == 0) {
        uint2 o;
        o.x = pk2(a0, a1);
        o.y = pk2(a2, a3);
        ((uint2*)aggb)[(size_t)n * 32 + cl] = o;
    }
}

// ---------------- BN stats from bf16 (raw sums) ----------------

__global__ __launch_bounds__(256) void stats_bf(const unsigned* __restrict__ v, int totalU,
                                                float* __restrict__ sums) {
    int tid = blockIdx.x * 256 + threadIdx.x;
    int stride = gridDim.x * 256;
    float sx = 0.f, sy = 0.f, qx = 0.f, qy = 0.f;
    for (int i = tid; i < totalU; i += stride) {
        unsigned u = v[i];
        float a = bflo(u), b = bfhi(u);
        sx += a; sy += b;
        qx = fmaf(a, a, qx); qy = fmaf(b, b, qy);
    }
    __shared__ float l0[256], l1[256], l2[256], l3[256];
    int t = threadIdx.x;
    l0[t] = sx; l1[t] = sy; l2[t] = qx; l3[t] = qy;
    __syncthreads();
    if (t < 64) {
        sx = (l0[t] + l0[t + 64]) + (l0[t + 128] + l0[t + 192]);
        sy = (l1[t] + l1[t + 64]) + (l1[t + 128] + l1[t + 192]);
        qx = (l2[t] + l2[t + 64]) + (l2[t + 128] + l2[t + 192]);
        qy = (l3[t] + l3[t + 64]) + (l3[t + 128] + l3[t + 192]);
        atomicAdd(&sums[2 * t], sx);
        atomicAdd(&sums[2 * t + 1], sy);
        atomicAdd(&sums[128 + 2 * t], qx);
        atomicAdd(&sums[128 + 2 * t + 1], qy);
    }
}

// ---------------- GEMM1 fused: x1 = relu(bn0(agg)) + proj (written out), h = x1 @ W1, LDS epilogue ----------------

__global__ __launch_bounds__(512) void mgemm1_fused(const uint4* __restrict__ aggb,
                                                    const uint4* __restrict__ projb,
                                                    const float* __restrict__ stats,
                                                    const float* __restrict__ g,
                                                    const float* __restrict__ be,
                                                    const ushortT* __restrict__ Wt1,
                                                    ushortT* __restrict__ O,
                                                    uint4* __restrict__ x1b,
                                                    int N) {
    __shared__ __align__(16) ushortT S[17408];
    __shared__ float sc[128], sh[128];
    int tid = threadIdx.x;
    int brow = blockIdx.x * 128;

    if (tid < 128) {
        float mean = stats[tid] / (float)N;
        float var = stats[128 + tid] / (float)N - mean * mean;
        float inv = rsqrtf(var + EPS);
        float s = g[tid] * inv;
        sc[tid] = s;
        sh[tid] = be[tid] - mean * s;
    }
    __syncthreads();

#pragma unroll
    for (int i = 0; i < 4; ++i) {
        int idx = i * 512 + tid;
        int row = idx >> 4, q = idx & 15;
        int gr = brow + row;
        uint4 a = make_uint4(0u, 0u, 0u, 0u), p = a;
        if (gr < N) {
            size_t gidx = (size_t)gr * 16 + q;
            a = aggb[gidx];
            p = projb[gidx];
        }
        int ch = q * 8;
        float v0 = fmaxf(fmaf(bflo(a.x), sc[ch + 0], sh[ch + 0]), 0.f) + bflo(p.x);
        float v1 = fmaxf(fmaf(bfhi(a.x), sc[ch + 1], sh[ch + 1]), 0.f) + bfhi(p.x);
        float v2 = fmaxf(fmaf(bflo(a.y), sc[ch + 2], sh[ch + 2]), 0.f) + bflo(p.y);
        float v3 = fmaxf(fmaf(bfhi(a.y), sc[ch + 3], sh[ch + 3]), 0.f) + bfhi(p.y);
        float v4 = fmaxf(fmaf(bflo(a.z), sc[ch + 4], sh[ch + 4]), 0.f) + bflo(p.z);
        float v5 = fmaxf(fmaf(bfhi(a.z), sc[ch + 5], sh[ch + 5]), 0.f) + bfhi(p.z);
        float v6 = fmaxf(fmaf(bflo(a.w), sc[ch + 6], sh[ch + 6]), 0.f) + bflo(p.w);
        float v7 = fmaxf(fmaf(bfhi(a.w), sc[ch + 7], sh[ch + 7]), 0.f) + bfhi(p.w);
        uint4 pv;
        pv.x = pk2(v0, v1);
        pv.y = pk2(v2, v3);
        pv.z = pk2(v4, v5);
        pv.w = pk2(v6, v7);
        *(uint4*)&S[row * 136 + q * 8] = pv;
        if (gr < N) x1b[(size_t)gr * 16 + q] = pv;
    }
    __syncthreads();

    int w = tid >> 6, lane = tid & 63;
    int lm = lane & 15, lk = lane >> 4;
    int rh = (w >> 2) * 64;
    int colbase = (w & 3) * 32;

    bf16x8 breg[2][4];
#pragma unroll
    for (int nt = 0; nt < 2; ++nt)
#pragma unroll
        for (int ks = 0; ks < 4; ++ks)
            breg[nt][ks] = *(const bf16x8*)&Wt1[(size_t)(colbase + nt * 16 + lm) * H + ks * 32 + lk * 8];

    f32x4 acc[4][2];
#pragma unroll
    for (int mt = 0; mt < 4; ++mt)
#pragma unroll
        for (int nt = 0; nt < 2; ++nt) acc[mt][nt] = (f32x4)0.f;

#pragma unroll
    for (int ks = 0; ks < 4; ++ks) {
        bf16x8 af[4];
#pragma unroll
        for (int mt = 0; mt < 4; ++mt)
            af[mt] = *(const bf16x8*)&S[(rh + mt * 16 + lm) * 136 + ks * 32 + lk * 8];
#pragma unroll
        for (int nt = 0; nt < 2; ++nt)
#pragma unroll
            for (int mt = 0; mt < 4; ++mt)
                acc[mt][nt] = __builtin_amdgcn_mfma_f32_16x16x32_bf16(af[mt], breg[nt][ks], acc[mt][nt], 0, 0, 0);
    }

    __syncthreads();
#pragma unroll
    for (int mt = 0; mt < 4; ++mt)
#pragma unroll
        for (int nt = 0; nt < 2; ++nt) {
            int col = colbase + nt * 16 + lm;
#pragma unroll
            for (int j = 0; j < 4; ++j) {
                int row = rh + mt * 16 + lk * 4 + j;
                S[row * 136 + col] = f2bf(acc[mt][nt][j]);
            }
        }
    __syncthreads();
#pragma unroll
    for (int i = 0; i < 4; ++i) {
        int idx = i * 512 + tid;
        int row = idx >> 4, colq = idx & 15;
        int gr = brow + row;
        if (gr < N) {
            uint4 v = *(const uint4*)&S[row * 136 + colq * 8];
            *(uint4*)&O[(size_t)gr * 128 + colq * 8] = v;
        }
    }
}

// ---------------- head: out = (relu(bn1(agg)) + x1) @ hW + hb, x2 inline ----------------

__global__ __launch_bounds__(256) void head_fused(const uint4* __restrict__ aggb,
                                                  const uint4* __restrict__ x1b,
                                                  const float* __restrict__ stats,
                                                  const float* __restrict__ g,
                                                  const float* __restrict__ be,
                                                  const ushortT* __restrict__ WtH,
                                                  const float* __restrict__ hb,
                                                  float* __restrict__ out, int N) {
    __shared__ __align__(16) ushortT As[64][136];
    __shared__ __align__(16) ushortT Bs[48][136];
    __shared__ float sc[128], sh[128];

    int tid = threadIdx.x;
    int brow = blockIdx.x * 64;
    int w = tid >> 6, lane = tid & 63;
    int lm = lane & 15, lk = lane >> 4;

    if (tid < 128) {
        float mean = stats[tid] / (float)N;
        float var = stats[128 + tid] / (float)N - mean * mean;
        float inv = rsqrtf(var + EPS);
        float s = g[tid] * inv;
        sc[tid] = s;
        sh[tid] = be[tid] - mean * s;
    }
    if (tid < 192) {
        int row = tid >> 2, q = tid & 3;
        const uint4* src = (const uint4*)&WtH[(size_t)row * H + q * 32];
        uint4 a = src[0], b = src[1], c = src[2], d = src[3];
        uint4* dst = (uint4*)&Bs[row][q * 32];
        dst[0] = a; dst[1] = b; dst[2] = c; dst[3] = d;
    }
    __syncthreads();
#pragma unroll
    for (int k = 0; k < 4; ++k) {
        int idx = k * 256 + tid;
        int row = idx >> 4, colq = idx & 15;
        int gr = brow + row;
        uint4 a = make_uint4(0u, 0u, 0u, 0u), x = a;
        if (gr < N) {
            size_t gidx = (size_t)brow * 16 + idx;
            a = aggb[gidx];
            x = x1b[gidx];
        }
        int ch = colq * 8;
        float v0 = fmaxf(fmaf(bflo(a.x), sc[ch + 0], sh[ch + 0]), 0.f) + bflo(x.x);
        float v1 = fmaxf(fmaf(bfhi(a.x), sc[ch + 1], sh[ch + 1]), 0.f) + bfhi(x.x);
        float v2 = fmaxf(fmaf(bflo(a.y), sc[ch + 2], sh[ch + 2]), 0.f) + bflo(x.y);
        float v3 = fmaxf(fmaf(bfhi(a.y), sc[ch + 3], sh[ch + 3]), 0.f) + bfhi(x.y);
        float v4 = fmaxf(fmaf(bflo(a.z), sc[ch + 4], sh[ch + 4]), 0.f) + bflo(x.z);
        float v5 = fmaxf(fmaf(bfhi(a.z), sc[ch + 5], sh[ch + 5]), 0.f) + bfhi(x.z);
        float v6 = fmaxf(fmaf(bflo(a.w), sc[ch + 6], sh[ch + 6]), 0.f) + bflo(x.w);
        float v7 = fmaxf(fmaf(bfhi(a.w), sc[ch + 7], sh[ch + 7]), 0.f) + bfhi(x.w);
        uint4 pv;
        pv.x = pk2(v0, v1);
        pv.y = pk2(v2, v3);
        pv.z = pk2(v4, v5);
        pv.w = pk2(v6, v7);
        *(uint4*)&As[row][colq * 8] = pv;
    }
    __syncthreads();

    f32x4 acc[3];
#pragma unroll
    for (int nt = 0; nt < 3; ++nt) acc[nt] = (f32x4)0.f;
#pragma unroll
    for (int ks = 0; ks < 4; ++ks) {
        bf16x8 a = *(const bf16x8*)&As[w * 16 + lm][ks * 32 + lk * 8];
#pragma unroll
        for (int nt = 0; nt < 3; ++nt) {
            bf16x8 b = *(const bf16x8*)&Bs[nt * 16 + lm][ks * 32 + lk * 8];
            acc[nt] = __builtin_amdgcn_mfma_f32_16x16x32_bf16(a, b, acc[nt], 0, 0, 0);
        }
    }
#pragma unroll
    for (int nt = 0; nt < 3; ++nt) {
        int col = nt * 16 + lm;
        if (col < OUT_DIM) {
            float bbv = hb[col];
#pragma unroll
            for (int j = 0; j < 4; ++j) {
                int r = brow + w * 16 + lk * 4 + j;
                if (r < N) out[(size_t)r * OUT_DIM + col] = acc[nt][j] + bbv;
            }
        }
    }
}

// ---------------- launch ----------------

extern "C" void kernel_launch(void* const* d_in, const int* in_sizes, int n_in,
                              void* d_out, int out_size, void* d_ws, size_t ws_size,
                              hipStream_t stream) {
    const float* x   = (const float*)d_in[0];
    const int*   ei  = (const int*)d_in[1];
    const float* W0  = (const float*)d_in[2];
    // d_in[3] = b0: cancels in BatchNorm
    const float* g0  = (const float*)d_in[4];
    const float* be0 = (const float*)d_in[5];
    const float* pW  = (const float*)d_in[6];
    const float* pb  = (const float*)d_in[7];
    const float* W1  = (const float*)d_in[8];
    // d_in[9] = b1: cancels in BatchNorm
    const float* g1  = (const float*)d_in[10];
    const float* be1 = (const float*)d_in[11];
    const float* hW  = (const float*)d_in[12];
    const float* hb  = (const float*)d_in[13];
    float* out = (float*)d_out;

    int N = in_sizes[0] / IN_DIM;
    int E = in_sizes[1] / 2;
    size_t NH = (size_t)N * H;

    // workspace layout (all bf16 intermediates)
    ushortT* hb16   = (ushortT*)d_ws;            // [N,128] conv input h
    ushortT* aggb   = hb16 + NH;                 // [N,128] aggregated
    ushortT* projb  = aggb + NH;                 // [N,128] proj (block0)
    ushortT* x1b    = projb + NH;                // [N,128] x1
    float*   dis    = (float*)(x1b + NH);        // [N]
    int*     cnt    = (int*)(dis + N);           // [N]
    int*     rowptr = cnt + N;                   // [N+1]
    int*     cursor = rowptr + (N + 1);          // [N]
    int2*    recs   = (int2*)(cursor + N);       // [E+N] (8B-aligned)
    float*   stats  = (float*)(recs + (E + N));  // [512]: conv0 then conv1
    ushortT* Wt0    = (ushortT*)(stats + 512);   // [128*256]
    ushortT* WtP    = Wt0 + 128 * 256;           // [128*256]
    ushortT* Wt1    = WtP + 128 * 256;           // [128*128]
    ushortT* WtH    = Wt1 + 128 * 128;           // [48*128]
    int*     bsum   = (int*)(WtH + 48 * 128);    // [256]
    int*     boff   = bsum + 256;                // [256]
    float*   stats0 = stats;
    float*   stats1 = stats + 256;

    int nb = (N + 255) / 256;
    int g64 = (N + 63) / 64;
    int g128 = (N + 127) / 128;
    int gAgg = (N + 3) / 4;
    int nper = (N + 7) / 8;
    int ntiles = g64;
    int gemmPersist = (ntiles + 1) / 2;          // 2 tiles per block
    const int CNT_BLOCKS = 1024;                 // count role blocks (multiple of 8)

    // prep (weights + zero cnt/stats)
    prep_weights<<<196, 256, 0, stream>>>(W0, pW, W1, hW, Wt0, WtP, Wt1, WtH, cnt, stats, N);

    // GEMM0 (persistent dual) + degree count in one dispatch
    gemm0_count<<<gemmPersist + CNT_BLOCKS, 512, 0, stream>>>(x, Wt0, WtP, pb, hb16, projb,
                                                              ei, cnt, N, E, nper,
                                                              gemmPersist, ntiles);

    // CSR offsets + records
    scan_block_sum<<<nb, 256, 0, stream>>>(cnt, bsum, dis, N);
    scan_tops<<<1, 256, 0, stream>>>(bsum, boff, &rowptr[N], nb);
    scan_final<<<nb, 256, 0, stream>>>(cnt, boff, dis, rowptr, cursor, recs, N);
    fill_xcd<<<2048, 256, 0, stream>>>(ei, E, nper, dis, cursor, recs);

    // block 0
    aggregate_rec<<<gAgg, 256, 0, stream>>>(hb16, rowptr, recs, aggb, N);
    stats_bf<<<256, 256, 0, stream>>>((const unsigned*)aggb, (int)(NH / 2), stats0);

    // block 1 (x1 = relu(bn0(agg)) + proj fused into GEMM1's staging; x1 also written for head)
    mgemm1_fused<<<g128, 512, 0, stream>>>((const uint4*)aggb, (const uint4*)projb, stats0, g0, be0,
                                           Wt1, hb16, (uint4*)x1b, N);
    aggregate_rec<<<gAgg, 256, 0, stream>>>(hb16, rowptr, recs, aggb, N);
    stats_bf<<<256, 256, 0, stream>>>((const unsigned*)aggb, (int)(NH / 2), stats1);

    // head (x2 computed inline)
    head_fused<<<g64, 256, 0, stream>>>((const uint4*)aggb, (const uint4*)x1b, stats1, g1, be1,
                                        WtH, hb, out, N);
}